// Round 1
// baseline (525.316 us; speedup 1.0000x reference)
//
#include <hip/hip_runtime.h>
#include <math.h>

// Problem constants (fixed by the reference): B=8, N=M=4096, C=256, H=W=64, KS=5.
#define EPSF 1e-6f

// ---------------------------------------------------------------------------
// Shared GEMM tile machinery: 128x128 tile, BK=32, 256 threads, 8x8 micro-tile.
// LDS layout: S[32][132] (k-outer, padded to 132 words: 16B-aligned rows, fewer
// bank conflicts on transposed staging writes).
// ---------------------------------------------------------------------------
#define TLD 132

// Stage a (row-major M x K, k-contiguous) tile transposed into S[k][m].
__device__ __forceinline__ void stage_t(const float* __restrict__ src, int ld, int row0, int c0,
                                        float (&S)[32][TLD], int tid) {
#pragma unroll
  for (int p = 0; p < 4; ++p) {
    int f = tid + p * 256;           // 0..1023 float4s: 128 rows x 8 f4
    int r = f >> 3, c4 = f & 7;
    const float4 v = *(const float4*)&src[(size_t)(row0 + r) * ld + c0 + c4 * 4];
    S[c4 * 4 + 0][r] = v.x;
    S[c4 * 4 + 1][r] = v.y;
    S[c4 * 4 + 2][r] = v.z;
    S[c4 * 4 + 3][r] = v.w;
  }
}

// Stage a (row-major K x N, n-contiguous) tile directly into S[k][n].
__device__ __forceinline__ void stage_n(const float* __restrict__ src, int ld, int k0, int n0,
                                        float (&S)[32][TLD], int tid) {
#pragma unroll
  for (int p = 0; p < 4; ++p) {
    int f = tid + p * 256;           // 32 rows x 32 f4
    int kk = f >> 5, n4 = f & 31;
    *(float4*)&S[kk][n4 * 4] = *(const float4*)&src[(size_t)(k0 + kk) * ld + n0 + n4 * 4];
  }
}

__device__ __forceinline__ void mm_inner(const float (&As)[32][TLD], const float (&Bs)[32][TLD],
                                         float (&acc)[8][8], int ty, int tx) {
#pragma unroll
  for (int kk = 0; kk < 32; ++kk) {
    const float4 a0 = *(const float4*)&As[kk][ty * 8];
    const float4 a1 = *(const float4*)&As[kk][ty * 8 + 4];
    const float4 b0 = *(const float4*)&Bs[kk][tx * 8];
    const float4 b1 = *(const float4*)&Bs[kk][tx * 8 + 4];
    const float a[8] = {a0.x, a0.y, a0.z, a0.w, a1.x, a1.y, a1.z, a1.w};
    const float b[8] = {b0.x, b0.y, b0.z, b0.w, b1.x, b1.y, b1.z, b1.w};
#pragma unroll
    for (int i = 0; i < 8; ++i)
#pragma unroll
      for (int j = 0; j < 8; ++j)
        acc[i][j] = fmaf(a[i], b[j], acc[i][j]);
  }
}

__device__ __forceinline__ float softplusf(float x) {
  return (x > 20.f) ? x : log1pf(expf(x));
}

// ---------------------------------------------------------------------------
// 1) Projections: out[r][d] = sum_c A[r][c] * W[d][c]; q/k get activation+cube.
//    grid (256, 2, 3): z selects {q, k, v}. Rows span all b*n = 32768.
// ---------------------------------------------------------------------------
__global__ __launch_bounds__(256) void proj_kernel(
    const float* __restrict__ query, const float* __restrict__ key, const float* __restrict__ value,
    const float* __restrict__ Wq, const float* __restrict__ Wk, const float* __restrict__ Wv,
    const float* __restrict__ scale,
    float* __restrict__ qb, float* __restrict__ kb, float* __restrict__ vb) {
  const int which = blockIdx.z;
  const float* A = (which == 0) ? query : (which == 1) ? key : value;
  const float* W = (which == 0) ? Wq : (which == 1) ? Wk : Wv;
  float* outp = (which == 0) ? qb : (which == 1) ? kb : vb;
  const bool act = (which < 2);

  __shared__ float As[32][TLD];
  __shared__ float Bs[32][TLD];
  const int tid = threadIdx.x;
  const int row0 = blockIdx.x * 128;  // global row (b*4096+n), 0..32767
  const int col0 = blockIdx.y * 128;  // output channel d

  float acc[8][8] = {};
  for (int ks = 0; ks < 8; ++ks) {
    const int c0 = ks * 32;
    stage_t(A, 256, row0, c0, As, tid);
    stage_t(W, 256, col0, c0, Bs, tid);
    __syncthreads();
    mm_inner(As, Bs, acc, tid >> 4, tid & 15);
    __syncthreads();
  }

  const int ty = tid >> 4, tx = tid & 15;
  float scv[8];
  if (act) {
#pragma unroll
    for (int j = 0; j < 8; ++j) scv[j] = softplusf(scale[col0 + tx * 8 + j]);
  }
#pragma unroll
  for (int i = 0; i < 8; ++i) {
    const size_t row = (size_t)row0 + ty * 8 + i;
    float o[8];
#pragma unroll
    for (int j = 0; j < 8; ++j) {
      float v = acc[i][j];
      if (act) {
        v = (fmaxf(v, 0.f) + EPSF) / scv[j];
        v = v * v * v;  // q**3 / ||q|| * ||q|| == q**3
      }
      o[j] = v;
    }
    *(float4*)&outp[row * 256 + col0 + tx * 8]     = make_float4(o[0], o[1], o[2], o[3]);
    *(float4*)&outp[row * 256 + col0 + tx * 8 + 4] = make_float4(o[4], o[5], o[6], o[7]);
  }
}

// ---------------------------------------------------------------------------
// 2) k_sum partials: grid (32, 8), block 256. Each block sums 128 m-rows.
// ---------------------------------------------------------------------------
__global__ __launch_bounds__(256) void ksum_part_kernel(const float* __restrict__ kb,
                                                        float* __restrict__ ksp) {
  const int b = blockIdx.y, ms = blockIdx.x, c = threadIdx.x;
  const float* base = kb + ((size_t)b * 4096 + ms * 128) * 256 + c;
  float a = 0.f;
  for (int m = 0; m < 128; ++m) a += base[(size_t)m * 256];
  ksp[((size_t)b * 32 + ms) * 256 + c] = a;
}

__global__ __launch_bounds__(256) void ksum_reduce_kernel(const float* __restrict__ ksp,
                                                          float* __restrict__ ksum) {
  const int b = blockIdx.x, c = threadIdx.x;
  float a = 0.f;
  for (int t = 0; t < 32; ++t) a += ksp[((size_t)b * 32 + t) * 256 + c];
  ksum[b * 256 + c] = a;
}

// ---------------------------------------------------------------------------
// 3) kv partials: kv[b][c][d] = sum_m k[b][m][c]*v[b][m][d].
//    grid (2, 2, 64): z = b*8 + s (m-split of 8, 512 rows each). No atomics.
// ---------------------------------------------------------------------------
__global__ __launch_bounds__(256) void kv_kernel(const float* __restrict__ kb,
                                                 const float* __restrict__ vb,
                                                 float* __restrict__ kvp) {
  const int b = blockIdx.z >> 3, s = blockIdx.z & 7;
  const int c0t = blockIdx.x * 128, d0t = blockIdx.y * 128;
  const float* K = kb + (size_t)b * 4096 * 256;
  const float* V = vb + (size_t)b * 4096 * 256;

  __shared__ float Ks[32][TLD];
  __shared__ float Vs[32][TLD];
  const int tid = threadIdx.x;
  float acc[8][8] = {};

  for (int mc = 0; mc < 16; ++mc) {
    const int m0 = s * 512 + mc * 32;
    stage_n(K, 256, m0, c0t, Ks, tid);  // Ks[m][c] — direct copy
    stage_n(V, 256, m0, d0t, Vs, tid);  // Vs[m][d]
    __syncthreads();
    mm_inner(Ks, Vs, acc, tid >> 4, tid & 15);
    __syncthreads();
  }

  const int ty = tid >> 4, tx = tid & 15;
  float* outp = kvp + ((size_t)b * 8 + s) * 65536;
#pragma unroll
  for (int i = 0; i < 8; ++i) {
    const size_t r = (size_t)c0t + ty * 8 + i;
    *(float4*)&outp[r * 256 + d0t + tx * 8] =
        make_float4(acc[i][0], acc[i][1], acc[i][2], acc[i][3]);
    *(float4*)&outp[r * 256 + d0t + tx * 8 + 4] =
        make_float4(acc[i][4], acc[i][5], acc[i][6], acc[i][7]);
  }
}

__global__ __launch_bounds__(256) void kv_reduce_kernel(const float* __restrict__ kvp,
                                                        float* __restrict__ kv) {
  const int idx = blockIdx.x * 256 + threadIdx.x;  // 524288 total
  const int b = idx >> 16, cd = idx & 65535;
  float s = 0.f;
#pragma unroll
  for (int t = 0; t < 8; ++t) s += kvp[((size_t)b * 8 + t) * 65536 + cd];
  kv[idx] = s;
}

// ---------------------------------------------------------------------------
// 4) z[b][n] = 1 / (q[b,n,:] . ksum[b,:] + eps). One wave per row.
// ---------------------------------------------------------------------------
__global__ __launch_bounds__(256) void z_kernel(const float* __restrict__ qb,
                                                const float* __restrict__ ksum,
                                                float* __restrict__ zb) {
  const int wid = threadIdx.x >> 6, lane = threadIdx.x & 63;
  const int row = blockIdx.x * 4 + wid;  // 0..32767
  const int b = row >> 12;
  const float4 qv = *(const float4*)&qb[(size_t)row * 256 + lane * 4];
  const float4 kc = *(const float4*)&ksum[b * 256 + lane * 4];
  float d = qv.x * kc.x + qv.y * kc.y + qv.z * kc.z + qv.w * kc.w;
#pragma unroll
  for (int off = 32; off > 0; off >>= 1) d += __shfl_xor(d, off, 64);
  if (lane == 0) zb[row] = 1.f / (d + EPSF);
}

// ---------------------------------------------------------------------------
// 5) x1[b][n][d] = (q[b,n,:] . kv[b,:,d]) * z[b,n], stored TRANSPOSED as
//    xt[b][d][n] (c-major) so the conv is fully coalesced. grid (32, 2, 8).
// ---------------------------------------------------------------------------
__global__ __launch_bounds__(256) void x1_kernel(const float* __restrict__ qb,
                                                 const float* __restrict__ kv,
                                                 const float* __restrict__ zb,
                                                 float* __restrict__ xt) {
  const int b = blockIdx.z;
  const int row0 = blockIdx.x * 128;  // n within batch
  const int col0 = blockIdx.y * 128;  // d
  const float* A = qb + (size_t)b * 4096 * 256;
  const float* Bm = kv + (size_t)b * 65536;

  __shared__ float As[32][TLD];
  __shared__ float Bs[32][TLD];
  const int tid = threadIdx.x;
  float acc[8][8] = {};

  for (int ks = 0; ks < 8; ++ks) {
    const int c0 = ks * 32;
    stage_t(A, 256, row0, c0, As, tid);
    stage_n(Bm, 256, c0, col0, Bs, tid);
    __syncthreads();
    mm_inner(As, Bs, acc, tid >> 4, tid & 15);
    __syncthreads();
  }

  const int ty = tid >> 4, tx = tid & 15;
  float zr[8];
#pragma unroll
  for (int i = 0; i < 8; ++i) zr[i] = zb[(size_t)b * 4096 + row0 + ty * 8 + i];
#pragma unroll
  for (int i = 0; i < 8; ++i)
#pragma unroll
    for (int j = 0; j < 8; ++j) acc[i][j] *= zr[i];

  // Transposed store via LDS restage (reuse As), 32 d-rows per chunk.
  for (int q4 = 0; q4 < 4; ++q4) {
    if ((tx >> 2) == q4) {
      const int txl = tx & 3;
#pragma unroll
      for (int i = 0; i < 8; ++i)
#pragma unroll
        for (int j = 0; j < 8; ++j)
          As[txl * 8 + j][ty * 8 + i] = acc[i][j];
    }
    __syncthreads();
#pragma unroll
    for (int p = 0; p < 4; ++p) {
      const int f = tid + p * 256;
      const int dd = f >> 5, n4 = f & 31;
      const float4 v = *(const float4*)&As[dd][n4 * 4];
      *(float4*)&xt[((size_t)b * 256 + col0 + q4 * 32 + dd) * 4096 + row0 + n4 * 4] = v;
    }
    __syncthreads();
  }
}

// ---------------------------------------------------------------------------
// 6) Depthwise 5x5 conv + bias on (B, C, 64, 64), zero ("SAME") padding.
//    One block per (b,c) plane; register sliding window: 5 LDS reads/pixel.
// ---------------------------------------------------------------------------
__global__ __launch_bounds__(256) void dwconv_kernel(const float* __restrict__ xt,
                                                     const float* __restrict__ w,
                                                     const float* __restrict__ bias,
                                                     float* __restrict__ xc) {
  const int bc = blockIdx.x;  // b*256 + c
  const int c = bc & 255;
  const float* plane = xt + (size_t)bc * 4096;
  float* oplane = xc + (size_t)bc * 4096;

  __shared__ float Ls[68][72];  // rows: 2 halo + 64 + 2; cols: interior at +4 (16B aligned)
  const int tid = threadIdx.x;

  for (int i = tid; i < 68 * 72; i += 256) ((float*)Ls)[i] = 0.f;
  __syncthreads();
#pragma unroll
  for (int p = 0; p < 4; ++p) {
    const int f = tid + p * 256;  // 1024 float4s = 64 rows x 16
    const int y = f >> 4, x4 = f & 15;
    *(float4*)&Ls[2 + y][4 + x4 * 4] = *(const float4*)&plane[y * 64 + x4 * 4];
  }
  __syncthreads();

  float wreg[25];
#pragma unroll
  for (int t = 0; t < 25; ++t) wreg[t] = w[c * 25 + t];
  const float bv = bias[c];

  const int x = tid & 63, ys0 = (tid >> 6) * 16;
  float win[5][5];
#pragma unroll
  for (int r = 0; r < 5; ++r)
#pragma unroll
    for (int cx = 0; cx < 5; ++cx) win[r][cx] = Ls[ys0 + r][x + 2 + cx];

  for (int yy = 0; yy < 16; ++yy) {
    float s = bv;
#pragma unroll
    for (int ky = 0; ky < 5; ++ky)
#pragma unroll
      for (int kx = 0; kx < 5; ++kx) s = fmaf(win[ky][kx], wreg[ky * 5 + kx], s);
    oplane[(ys0 + yy) * 64 + x] = s;
    if (yy < 15) {
#pragma unroll
      for (int r = 0; r < 4; ++r)
#pragma unroll
        for (int cx = 0; cx < 5; ++cx) win[r][cx] = win[r + 1][cx];
#pragma unroll
      for (int cx = 0; cx < 5; ++cx) win[4][cx] = Ls[ys0 + yy + 5][x + 2 + cx];
    }
  }
}

// ---------------------------------------------------------------------------
// 7) Final: out[b][n][dd] = sum_c (xc[b][c][n] + q[b][n][c]) * Wproj[dd][c] + bproj[dd]
//    A-tile fuses the transpose-add during staging. grid (32, 2, 8).
// ---------------------------------------------------------------------------
__global__ __launch_bounds__(256) void final_kernel(const float* __restrict__ xc,
                                                    const float* __restrict__ qb,
                                                    const float* __restrict__ Wp,
                                                    const float* __restrict__ bp,
                                                    float* __restrict__ outp) {
  const int b = blockIdx.z;
  const int row0 = blockIdx.x * 128;  // n within batch
  const int col0 = blockIdx.y * 128;  // dd
  const float* Q = qb + (size_t)b * 4096 * 256;
  const float* XC = xc + (size_t)b * 256 * 4096;

  __shared__ float As[32][TLD];
  __shared__ float Bs[32][TLD];
  const int tid = threadIdx.x;
  float acc[8][8] = {};

  for (int ks = 0; ks < 8; ++ks) {
    const int c0 = ks * 32;
    stage_t(Q, 256, row0, c0, As, tid);   // As[c][n] = q
    stage_t(Wp, 256, col0, c0, Bs, tid);  // Bs[c][dd]
    __syncthreads();
    // As[c][n] += xc[c][n]  (both coalesced: xc rows are n-contiguous)
#pragma unroll
    for (int p = 0; p < 4; ++p) {
      const int f = tid + p * 256;
      const int kk = f >> 5, n4 = f & 31;
      const float4 v = *(const float4*)&XC[(size_t)(c0 + kk) * 4096 + row0 + n4 * 4];
      float4 cur = *(const float4*)&As[kk][n4 * 4];
      cur.x += v.x; cur.y += v.y; cur.z += v.z; cur.w += v.w;
      *(float4*)&As[kk][n4 * 4] = cur;
    }
    __syncthreads();
    mm_inner(As, Bs, acc, tid >> 4, tid & 15);
    __syncthreads();
  }

  const int ty = tid >> 4, tx = tid & 15;
  float bpr[8];
#pragma unroll
  for (int j = 0; j < 8; ++j) bpr[j] = bp[col0 + tx * 8 + j];
#pragma unroll
  for (int i = 0; i < 8; ++i) {
    const size_t row = (size_t)b * 4096 + row0 + ty * 8 + i;
    *(float4*)&outp[row * 256 + col0 + tx * 8] =
        make_float4(acc[i][0] + bpr[0], acc[i][1] + bpr[1], acc[i][2] + bpr[2], acc[i][3] + bpr[3]);
    *(float4*)&outp[row * 256 + col0 + tx * 8 + 4] =
        make_float4(acc[i][4] + bpr[4], acc[i][5] + bpr[5], acc[i][6] + bpr[6], acc[i][7] + bpr[7]);
  }
}

// ---------------------------------------------------------------------------
extern "C" void kernel_launch(void* const* d_in, const int* in_sizes, int n_in,
                              void* d_out, int out_size, void* d_ws, size_t ws_size,
                              hipStream_t stream) {
  const float* query = (const float*)d_in[0];
  const float* key   = (const float*)d_in[1];
  const float* value = (const float*)d_in[2];
  const float* Wq    = (const float*)d_in[3];
  const float* Wk    = (const float*)d_in[4];
  const float* Wv    = (const float*)d_in[5];
  const float* Wproj = (const float*)d_in[6];
  const float* bproj = (const float*)d_in[7];
  const float* dwc_w = (const float*)d_in[8];
  const float* dwc_b = (const float*)d_in[9];
  const float* scale = (const float*)d_in[10];
  // d_in[11], d_in[12] = H, W (fixed 64x64)

  // Workspace layout (floats). Total ~114.4 MiB.
  float* ws  = (float*)d_ws;
  float* qb  = ws;                                   // 8*4096*256
  float* kb  = qb + (size_t)8 * 4096 * 256;          // 8*4096*256
  float* vb  = kb + (size_t)8 * 4096 * 256;          // 8*4096*256 (later reused as xt)
  float* kvp = vb + (size_t)8 * 4096 * 256;          // 8*8*65536
  float* kvb = kvp + (size_t)8 * 8 * 65536;          // 8*65536
  float* ksp = kvb + (size_t)8 * 65536;              // 8*32*256
  float* ksm = ksp + (size_t)8 * 32 * 256;           // 8*256
  float* zb  = ksm + (size_t)8 * 256;                // 8*4096
  float* outp = (float*)d_out;

  const dim3 blk(256);
  proj_kernel<<<dim3(256, 2, 3), blk, 0, stream>>>(query, key, value, Wq, Wk, Wv, scale,
                                                   qb, kb, vb);
  ksum_part_kernel<<<dim3(32, 8), blk, 0, stream>>>(kb, ksp);
  ksum_reduce_kernel<<<dim3(8), blk, 0, stream>>>(ksp, ksm);
  kv_kernel<<<dim3(2, 2, 64), blk, 0, stream>>>(kb, vb, kvp);
  kv_reduce_kernel<<<dim3(2048), blk, 0, stream>>>(kvp, kvb);
  z_kernel<<<dim3(8192), blk, 0, stream>>>(qb, ksm, zb);
  x1_kernel<<<dim3(32, 2, 8), blk, 0, stream>>>(qb, kvb, zb, vb /* xt */);
  dwconv_kernel<<<dim3(2048), blk, 0, stream>>>(vb /* xt */, dwc_w, dwc_b, kb /* xc */);
  final_kernel<<<dim3(32, 2, 8), blk, 0, stream>>>(kb /* xc */, qb, Wproj, bproj, outp);
}

// Round 3
// 319.742 us; speedup vs baseline: 1.6429x; 1.6429x over previous
//
#include <hip/hip_runtime.h>
#include <math.h>
#include <stdint.h>

// B=8, N=M=4096, C=256, H=W=64, KS=5 (fixed by reference).
#define EPSF 1e-6f

typedef _Float16 half_t;
typedef _Float16 half8 __attribute__((ext_vector_type(8)));
typedef _Float16 half4 __attribute__((ext_vector_type(4)));
typedef float f32x4 __attribute__((ext_vector_type(4)));

#define MFMA16(A, B, C) __builtin_amdgcn_mfma_f32_16x16x32_f16(A, B, C, 0, 0, 0)

__device__ __forceinline__ float softplusf(float x) {
  return (x > 20.f) ? x : log1pf(expf(x));
}

// --------------------------------------------------------------------------
// Shared MFMA-GEMM machinery. Tile 128x128, BK=32, 256 threads (4 waves 2x2),
// each wave computes 64x64 = 4x4 frags of 16x16x32 f16 MFMA, 3-term hi/lo
// split for ~fp32 accuracy. LDS tile layout [row][32] half, row = 64 B:
// wave's frag ds_read_b128 covers a contiguous 1 KiB region (m97-proven).
// --------------------------------------------------------------------------

// fp32 source staging: load float4, split to hi/lo halves in registers.
__device__ __forceinline__ void stage_f32split(const float* __restrict__ src, int ld,
                                               int row0, int k0,
                                               half_t* __restrict__ Dh, half_t* __restrict__ Dl,
                                               int tid) {
#pragma unroll
  for (int r = 0; r < 4; ++r) {
    const int f = tid + r * 256;          // 128 rows x 8 float4
    const int row = f >> 3, c4 = f & 7;
    const float4 v = *(const float4*)&src[(size_t)(row0 + row) * ld + k0 + c4 * 4];
    half4 h, l;
    h.x = (half_t)v.x; l.x = (half_t)(v.x - (float)h.x);
    h.y = (half_t)v.y; l.y = (half_t)(v.y - (float)h.y);
    h.z = (half_t)v.z; l.z = (half_t)(v.z - (float)h.z);
    h.w = (half_t)v.w; l.w = (half_t)(v.w - (float)h.w);
    *(half4*)&Dh[row * 32 + c4 * 4] = h;
    *(half4*)&Dl[row * 32 + c4 * 4] = l;
  }
}

// pre-split half plane staging via async global->LDS, 16 B per lane.
// LDS dest is wave-uniform base + lane*16 (linear layout matches exactly).
// Pointer casts via uintptr_t (CK amd_direct_load pattern) for compile safety.
__device__ __forceinline__ void stage_gld(const half_t* __restrict__ src, size_t rowbase,
                                          int ld, int k0, half_t* __restrict__ dst, int tid) {
#pragma unroll
  for (int r = 0; r < 2; ++r) {
    const int f = tid + r * 256;          // 128 rows x 4 chunks of 8 halfs
    const half_t* g = src + (rowbase + (size_t)(f >> 2)) * (size_t)ld + k0 + (f & 3) * 8;
    const __attribute__((address_space(1))) unsigned int* gp =
        (const __attribute__((address_space(1))) unsigned int*)(uintptr_t)g;
    __attribute__((address_space(3))) unsigned int* lp =
        (__attribute__((address_space(3))) unsigned int*)(uintptr_t)(dst + f * 8);
    __builtin_amdgcn_global_load_lds(gp, lp, 16, 0, 0);
  }
}

__device__ __forceinline__ void frag_compute(const half_t* __restrict__ As_h,
                                             const half_t* __restrict__ As_l,
                                             const half_t* __restrict__ Bs_h,
                                             const half_t* __restrict__ Bs_l,
                                             f32x4 (&acc)[4][4], int lane, int wm, int wn) {
  const int lr = lane & 15, lg = lane >> 4;
  half8 ah[4], al[4], bh[4], bl[4];
#pragma unroll
  for (int i = 0; i < 4; ++i) {
    const int ar = (wm * 64 + i * 16 + lr) * 32 + lg * 8;
    ah[i] = *(const half8*)&As_h[ar];
    al[i] = *(const half8*)&As_l[ar];
    const int br = (wn * 64 + i * 16 + lr) * 32 + lg * 8;
    bh[i] = *(const half8*)&Bs_h[br];
    bl[i] = *(const half8*)&Bs_l[br];
  }
#pragma unroll
  for (int i = 0; i < 4; ++i)
#pragma unroll
    for (int j = 0; j < 4; ++j) {
      acc[i][j] = MFMA16(ah[i], bh[j], acc[i][j]);
      acc[i][j] = MFMA16(ah[i], bl[j], acc[i][j]);
      acc[i][j] = MFMA16(al[i], bh[j], acc[i][j]);
    }
}

// --------------------------------------------------------------------------
// 1) Projections. out[r][d] = sum_c A[r][c]*W[d][c]; q/k: act + cube
//    (q**3/||q||*||q|| == q**3). which=0: q -> hi/lo planes [n][c].
//    which=1: k3 -> transposed [b][c][m]. which=2: v -> transposed [b][d][m].
//    D-frag: lane holds 4 consecutive rows (m) for one col -> half4 stores.
// --------------------------------------------------------------------------
__global__ __launch_bounds__(256) void proj_mfma(
    const float* __restrict__ query, const float* __restrict__ key,
    const float* __restrict__ value,
    const float* __restrict__ Wq, const float* __restrict__ Wk, const float* __restrict__ Wv,
    const float* __restrict__ scale,
    half_t* __restrict__ qh, half_t* __restrict__ ql,
    half_t* __restrict__ khT, half_t* __restrict__ klT,
    half_t* __restrict__ vhT, half_t* __restrict__ vlT) {
  const int which = blockIdx.z;
  const float* A = which == 0 ? query : which == 1 ? key : value;
  const float* W = which == 0 ? Wq : which == 1 ? Wk : Wv;
  const int row0 = blockIdx.x * 128, col0 = blockIdx.y * 128;
  const int tid = threadIdx.x;
  __shared__ __align__(16) half_t As_h[4096], As_l[4096], Bs_h[4096], Bs_l[4096];
  f32x4 acc[4][4] = {};
  const int lane = tid & 63, wave = tid >> 6, wm = wave >> 1, wn = wave & 1;
  const int lr = lane & 15, lg = lane >> 4;

  for (int ks = 0; ks < 8; ++ks) {
    const int k0 = ks * 32;
    stage_f32split(A, 256, row0, k0, As_h, As_l, tid);
    stage_f32split(W, 256, col0, k0, Bs_h, Bs_l, tid);
    __syncthreads();
    frag_compute(As_h, As_l, Bs_h, Bs_l, acc, lane, wm, wn);
    __syncthreads();
  }

  if (which == 0) {
#pragma unroll
    for (int j = 0; j < 4; ++j) {
      const int c = col0 + wn * 64 + j * 16 + lr;
      const float sc = softplusf(scale[c]);
#pragma unroll
      for (int i = 0; i < 4; ++i) {
        const size_t rb = (size_t)row0 + wm * 64 + i * 16 + lg * 4;
#pragma unroll
        for (int r = 0; r < 4; ++r) {
          float v = acc[i][j][r];
          v = (fmaxf(v, 0.f) + EPSF) / sc;
          v = v * v * v;
          const half_t h = (half_t)v;
          qh[(rb + r) * 256 + c] = h;
          ql[(rb + r) * 256 + c] = (half_t)(v - (float)h);
        }
      }
    }
  } else {
    const int b = row0 >> 12, m0 = row0 & 4095;
    half_t* Th = (which == 1) ? khT : vhT;
    half_t* Tl = (which == 1) ? klT : vlT;
    const bool act = (which == 1);
#pragma unroll
    for (int j = 0; j < 4; ++j) {
      const int c = col0 + wn * 64 + j * 16 + lr;
      const float sc = act ? softplusf(scale[c]) : 1.f;
#pragma unroll
      for (int i = 0; i < 4; ++i) {
        const int m = m0 + wm * 64 + i * 16 + lg * 4;
        half4 hv, lv;
#pragma unroll
        for (int r = 0; r < 4; ++r) {
          float v = acc[i][j][r];
          if (act) { v = (fmaxf(v, 0.f) + EPSF) / sc; v = v * v * v; }
          const half_t h = (half_t)v;
          hv[r] = h;
          lv[r] = (half_t)(v - (float)h);
        }
        *(half4*)&Th[(size_t)(b * 256 + c) * 4096 + m] = hv;
        *(half4*)&Tl[(size_t)(b * 256 + c) * 4096 + m] = lv;
      }
    }
  }
}

// --------------------------------------------------------------------------
// 2) ksum[b][c] = sum_m k3[b][m][c], from transposed planes (m contiguous).
// --------------------------------------------------------------------------
__global__ __launch_bounds__(256) void ksum_k(const half_t* __restrict__ khT,
                                              const half_t* __restrict__ klT,
                                              float* __restrict__ ksm) {
  const int bc = blockIdx.x;  // b*256 + c
  const size_t base = (size_t)bc * 4096 + threadIdx.x * 16;
  float s = 0.f;
#pragma unroll
  for (int p = 0; p < 2; ++p) {
    const half8 h = *(const half8*)&khT[base + p * 8];
    const half8 l = *(const half8*)&klT[base + p * 8];
#pragma unroll
    for (int u = 0; u < 8; ++u) s += (float)h[u] + (float)l[u];
  }
  __shared__ float rbuf[256];
  rbuf[threadIdx.x] = s;
  __syncthreads();
  for (int off = 128; off > 0; off >>= 1) {
    if (threadIdx.x < off) rbuf[threadIdx.x] += rbuf[threadIdx.x + off];
    __syncthreads();
  }
  if (threadIdx.x == 0) ksm[bc] = rbuf[0];
}

// --------------------------------------------------------------------------
// 3) kv partials: kvT[d][c] = sum_m v[m][d]*k3[m][c]. A = vT (rows d),
//    B = k3T (rows c), reduction dim m. m-split S=8 (512 m each), fp32 out.
// --------------------------------------------------------------------------
__global__ __launch_bounds__(256) void kv_mfma(
    const half_t* __restrict__ vhT, const half_t* __restrict__ vlT,
    const half_t* __restrict__ khT, const half_t* __restrict__ klT,
    float* __restrict__ kvp) {
  const int b = blockIdx.z >> 3, s = blockIdx.z & 7;
  const int d0 = blockIdx.x * 128, c0 = blockIdx.y * 128;
  const int tid = threadIdx.x;
  __shared__ __align__(16) half_t As_h[4096], As_l[4096], Bs_h[4096], Bs_l[4096];
  f32x4 acc[4][4] = {};
  const int lane = tid & 63, wave = tid >> 6, wm = wave >> 1, wn = wave & 1;
  const int lr = lane & 15, lg = lane >> 4;
  const size_t arow = (size_t)b * 256 + d0, brow = (size_t)b * 256 + c0;

  for (int ks = 0; ks < 16; ++ks) {
    const int k0 = s * 512 + ks * 32;
    stage_gld(vhT, arow, 4096, k0, As_h, tid);
    stage_gld(vlT, arow, 4096, k0, As_l, tid);
    stage_gld(khT, brow, 4096, k0, Bs_h, tid);
    stage_gld(klT, brow, 4096, k0, Bs_l, tid);
    __syncthreads();
    frag_compute(As_h, As_l, Bs_h, Bs_l, acc, lane, wm, wn);
    __syncthreads();
  }

  float* outp = kvp + ((size_t)(b * 8 + s)) * 65536;
#pragma unroll
  for (int j = 0; j < 4; ++j) {
    const int c = c0 + wn * 64 + j * 16 + lr;
#pragma unroll
    for (int i = 0; i < 4; ++i) {
      const int d = d0 + wm * 64 + i * 16 + lg * 4;
#pragma unroll
      for (int r = 0; r < 4; ++r) outp[(size_t)(d + r) * 256 + c] = acc[i][j][r];
    }
  }
}

__global__ __launch_bounds__(256) void kv_red(const float* __restrict__ kvp,
                                              half_t* __restrict__ kvTh,
                                              half_t* __restrict__ kvTl) {
  const size_t idx = (size_t)blockIdx.x * 256 + threadIdx.x;  // 524288
  const int b = (int)(idx >> 16);
  const int dc = (int)(idx & 65535);
  float s = 0.f;
#pragma unroll
  for (int t = 0; t < 8; ++t) s += kvp[((size_t)(b * 8 + t)) * 65536 + dc];
  const half_t h = (half_t)s;
  kvTh[idx] = h;
  kvTl[idx] = (half_t)(s - (float)h);
}

// --------------------------------------------------------------------------
// 4) z[b][n] = 1/(q3[b,n,:].ksum[b,:] + eps). One wave per row.
// --------------------------------------------------------------------------
__global__ __launch_bounds__(256) void z_k(const half_t* __restrict__ qh,
                                           const half_t* __restrict__ ql,
                                           const float* __restrict__ ksm,
                                           float* __restrict__ zb) {
  const int wid = threadIdx.x >> 6, lane = threadIdx.x & 63;
  const int row = blockIdx.x * 4 + wid;  // 0..32767
  const int b = row >> 12;
  const half4 h = *(const half4*)&qh[(size_t)row * 256 + lane * 4];
  const half4 l = *(const half4*)&ql[(size_t)row * 256 + lane * 4];
  const float4 kc = *(const float4*)&ksm[b * 256 + lane * 4];
  float d = ((float)h[0] + (float)l[0]) * kc.x + ((float)h[1] + (float)l[1]) * kc.y +
            ((float)h[2] + (float)l[2]) * kc.z + ((float)h[3] + (float)l[3]) * kc.w;
#pragma unroll
  for (int off = 32; off > 0; off >>= 1) d += __shfl_xor(d, off, 64);
  if (lane == 0) zb[row] = 1.f / (d + EPSF);
}

// --------------------------------------------------------------------------
// 5) x1[n][d] = (q3[n,:].kvT[d,:]) * z[n], stored TRANSPOSED fp32 as
//    xt[b][d][n]. D-frag lane holds 4 consecutive n for one d -> float4.
// --------------------------------------------------------------------------
__global__ __launch_bounds__(256) void x1_mfma(
    const half_t* __restrict__ qh, const half_t* __restrict__ ql,
    const half_t* __restrict__ kvTh, const half_t* __restrict__ kvTl,
    const float* __restrict__ zb, float* __restrict__ xt) {
  const int b = blockIdx.z, n0 = blockIdx.x * 128, d0t = blockIdx.y * 128;
  const int tid = threadIdx.x;
  __shared__ __align__(16) half_t As_h[4096], As_l[4096], Bs_h[4096], Bs_l[4096];
  f32x4 acc[4][4] = {};
  const int lane = tid & 63, wave = tid >> 6, wm = wave >> 1, wn = wave & 1;
  const int lr = lane & 15, lg = lane >> 4;
  const size_t arow = (size_t)b * 4096 + n0, brow = (size_t)b * 256 + d0t;

  for (int ks = 0; ks < 8; ++ks) {
    const int k0 = ks * 32;
    stage_gld(qh, arow, 256, k0, As_h, tid);
    stage_gld(ql, arow, 256, k0, As_l, tid);
    stage_gld(kvTh, brow, 256, k0, Bs_h, tid);
    stage_gld(kvTl, brow, 256, k0, Bs_l, tid);
    __syncthreads();
    frag_compute(As_h, As_l, Bs_h, Bs_l, acc, lane, wm, wn);
    __syncthreads();
  }

#pragma unroll
  for (int i = 0; i < 4; ++i) {
    const int nb = n0 + wm * 64 + i * 16 + lg * 4;
    float zr[4];
#pragma unroll
    for (int r = 0; r < 4; ++r) zr[r] = zb[b * 4096 + nb + r];
#pragma unroll
    for (int j = 0; j < 4; ++j) {
      const int d = d0t + wn * 64 + j * 16 + lr;
      *(float4*)&xt[((size_t)b * 256 + d) * 4096 + nb] =
          make_float4(acc[i][j][0] * zr[0], acc[i][j][1] * zr[1],
                      acc[i][j][2] * zr[2], acc[i][j][3] * zr[3]);
    }
  }
}

// --------------------------------------------------------------------------
// 6) Depthwise 5x5 conv + bias on (B,C,64,64) planes (R1-verified).
// --------------------------------------------------------------------------
__global__ __launch_bounds__(256) void dwconv_kernel(const float* __restrict__ xt,
                                                     const float* __restrict__ w,
                                                     const float* __restrict__ bias,
                                                     float* __restrict__ xc) {
  const int bc = blockIdx.x;  // b*256 + c
  const int c = bc & 255;
  const float* plane = xt + (size_t)bc * 4096;
  float* oplane = xc + (size_t)bc * 4096;

  __shared__ float Ls[68][72];
  const int tid = threadIdx.x;
  for (int i = tid; i < 68 * 72; i += 256) ((float*)Ls)[i] = 0.f;
  __syncthreads();
#pragma unroll
  for (int p = 0; p < 4; ++p) {
    const int f = tid + p * 256;
    const int y = f >> 4, x4 = f & 15;
    *(float4*)&Ls[2 + y][4 + x4 * 4] = *(const float4*)&plane[y * 64 + x4 * 4];
  }
  __syncthreads();

  float wreg[25];
#pragma unroll
  for (int t = 0; t < 25; ++t) wreg[t] = w[c * 25 + t];
  const float bv = bias[c];

  const int x = tid & 63, ys0 = (tid >> 6) * 16;
  float win[5][5];
#pragma unroll
  for (int r = 0; r < 5; ++r)
#pragma unroll
    for (int cx = 0; cx < 5; ++cx) win[r][cx] = Ls[ys0 + r][x + 2 + cx];

  for (int yy = 0; yy < 16; ++yy) {
    float s = bv;
#pragma unroll
    for (int ky = 0; ky < 5; ++ky)
#pragma unroll
      for (int kx = 0; kx < 5; ++kx) s = fmaf(win[ky][kx], wreg[ky * 5 + kx], s);
    oplane[(ys0 + yy) * 64 + x] = s;
    if (yy < 15) {
#pragma unroll
      for (int r = 0; r < 4; ++r)
#pragma unroll
        for (int cx = 0; cx < 5; ++cx) win[r][cx] = win[r + 1][cx];
#pragma unroll
      for (int cx = 0; cx < 5; ++cx) win[4][cx] = Ls[ys0 + yy + 5][x + 2 + cx];
    }
  }
}

// --------------------------------------------------------------------------
// 7) final: out[n][dd] = sum_c (xc[c][n] + q3[n][c]) * Wp[dd][c] + bp[dd].
//    xc transposed via small LDS buffer (stride 130); sum re-split to hi/lo.
// --------------------------------------------------------------------------
__global__ __launch_bounds__(256) void final_mfma(
    const half_t* __restrict__ qh, const half_t* __restrict__ ql,
    const float* __restrict__ xc, const float* __restrict__ Wp,
    const float* __restrict__ bp, float* __restrict__ outp) {
  const int b = blockIdx.z, n0 = blockIdx.x * 128, dd0 = blockIdx.y * 128;
  const int tid = threadIdx.x;
  __shared__ __align__(16) half_t As_h[4096], As_l[4096], Bs_h[4096], Bs_l[4096];
  __shared__ __align__(16) float Xs[32 * 130];
  f32x4 acc[4][4] = {};
  const int lane = tid & 63, wave = tid >> 6, wm = wave >> 1, wn = wave & 1;
  const int lr = lane & 15, lg = lane >> 4;

  for (int ks = 0; ks < 8; ++ks) {
    const int k0 = ks * 32;
    // xc tile [32 c][128 n] -> Xs (coalesced loads)
#pragma unroll
    for (int r = 0; r < 4; ++r) {
      const int f = tid + r * 256, cc = f >> 5, n4 = f & 31;
      const float4 v = *(const float4*)&xc[((size_t)b * 256 + k0 + cc) * 4096 + n0 + n4 * 4];
      *(float2*)&Xs[cc * 130 + n4 * 4] = make_float2(v.x, v.y);
      *(float2*)&Xs[cc * 130 + n4 * 4 + 2] = make_float2(v.z, v.w);
    }
    stage_f32split(Wp, 256, dd0, k0, Bs_h, Bs_l, tid);
    __syncthreads();
    // A = q3 + xc^T, split to hi/lo
#pragma unroll
    for (int r = 0; r < 2; ++r) {
      const int f = tid + r * 256, row = f >> 2, ch = f & 3;
      const size_t qoff = ((size_t)b * 4096 + n0 + row) * 256 + k0 + ch * 8;
      const half8 h8 = *(const half8*)&qh[qoff];
      const half8 l8 = *(const half8*)&ql[qoff];
      half8 oh, ol;
#pragma unroll
      for (int u = 0; u < 8; ++u) {
        const float v = (float)h8[u] + (float)l8[u] + Xs[(ch * 8 + u) * 130 + row];
        const half_t h = (half_t)v;
        oh[u] = h;
        ol[u] = (half_t)(v - (float)h);
      }
      *(half8*)&As_h[row * 32 + ch * 8] = oh;
      *(half8*)&As_l[row * 32 + ch * 8] = ol;
    }
    __syncthreads();
    frag_compute(As_h, As_l, Bs_h, Bs_l, acc, lane, wm, wn);
    __syncthreads();
  }

#pragma unroll
  for (int j = 0; j < 4; ++j) {
    const int dd = dd0 + wn * 64 + j * 16 + lr;
    const float bb = bp[dd];
#pragma unroll
    for (int i = 0; i < 4; ++i) {
      const size_t rowg = (size_t)b * 4096 + n0 + wm * 64 + i * 16 + lg * 4;
#pragma unroll
      for (int r = 0; r < 4; ++r) outp[(rowg + r) * 256 + dd] = acc[i][j][r] + bb;
    }
  }
}

// --------------------------------------------------------------------------
extern "C" void kernel_launch(void* const* d_in, const int* in_sizes, int n_in,
                              void* d_out, int out_size, void* d_ws, size_t ws_size,
                              hipStream_t stream) {
  const float* query = (const float*)d_in[0];
  const float* key   = (const float*)d_in[1];
  const float* value = (const float*)d_in[2];
  const float* Wq    = (const float*)d_in[3];
  const float* Wk    = (const float*)d_in[4];
  const float* Wv    = (const float*)d_in[5];
  const float* Wproj = (const float*)d_in[6];
  const float* bproj = (const float*)d_in[7];
  const float* dwc_w = (const float*)d_in[8];
  const float* dwc_b = (const float*)d_in[9];
  const float* scale = (const float*)d_in[10];

  // Workspace layout. U = 8*4096*256 elems. Peak ~119.7 MB (< R0's 119.9 MB).
  const size_t U = (size_t)8 * 4096 * 256;
  half_t* qh  = (half_t*)d_ws;            // U halfs, [b][n][c]
  half_t* ql  = qh + U;
  half_t* khT = ql + U;                   // [b][c][m] transposed
  half_t* klT = khT + U;
  half_t* vhT = klT + U;                  // [b][d][m] transposed
  half_t* vlT = vhT + U;
  float*  kvp = (float*)(vlT + U);        // 8*8*65536 fp32 partials
  half_t* kvTh = (half_t*)(kvp + (size_t)8 * 8 * 65536);  // [b][d][c]
  half_t* kvTl = kvTh + (size_t)8 * 65536;
  float*  ksm = (float*)(kvTl + (size_t)8 * 65536);       // [b][256]
  float*  zbuf = ksm + 8 * 256;                            // [32768]
  // aliases (reuse dead regions):
  float* xt = (float*)khT;  // x^T fp32 [b][d][n]  (khT/klT dead after kv)
  float* xc = (float*)vhT;  // conv out [b][c][n]  (vhT/vlT dead after kv)
  float* outp = (float*)d_out;

  const dim3 blk(256);
  proj_mfma<<<dim3(256, 2, 3), blk, 0, stream>>>(query, key, value, Wq, Wk, Wv, scale,
                                                 qh, ql, khT, klT, vhT, vlT);
  ksum_k<<<dim3(2048), blk, 0, stream>>>(khT, klT, ksm);
  kv_mfma<<<dim3(2, 2, 64), blk, 0, stream>>>(vhT, vlT, khT, klT, kvp);
  kv_red<<<dim3(2048), blk, 0, stream>>>(kvp, kvTh, kvTl);
  z_k<<<dim3(8192), blk, 0, stream>>>(qh, ql, ksm, zbuf);
  x1_mfma<<<dim3(32, 2, 8), blk, 0, stream>>>(qh, ql, kvTh, kvTl, zbuf, xt);
  dwconv_kernel<<<dim3(2048), blk, 0, stream>>>(xt, dwc_w, dwc_b, xc);
  final_mfma<<<dim3(32, 2, 8), blk, 0, stream>>>(qh, ql, xc, Wproj, bproj, outp);
}

// Round 4
// 309.532 us; speedup vs baseline: 1.6971x; 1.0330x over previous
//
#include <hip/hip_runtime.h>
#include <math.h>
#include <stdint.h>

// B=8, N=M=4096, C=256, H=W=64, KS=5 (fixed by reference).
#define EPSF 1e-6f

typedef _Float16 half_t;
typedef _Float16 half8 __attribute__((ext_vector_type(8)));
typedef _Float16 half4 __attribute__((ext_vector_type(4)));
typedef float f32x4 __attribute__((ext_vector_type(4)));

#define MFMA16(A, B, C) __builtin_amdgcn_mfma_f32_16x16x32_f16(A, B, C, 0, 0, 0)

__device__ __forceinline__ float softplusf(float x) {
  return (x > 20.f) ? x : log1pf(expf(x));
}

__device__ __forceinline__ void split4(const float4 v, half4& h, half4& l) {
  h.x = (half_t)v.x; l.x = (half_t)(v.x - (float)h.x);
  h.y = (half_t)v.y; l.y = (half_t)(v.y - (float)h.y);
  h.z = (half_t)v.z; l.z = (half_t)(v.z - (float)h.z);
  h.w = (half_t)v.w; l.w = (half_t)(v.w - (float)h.w);
}

// --------------------------------------------------------------------------
// Shared MFMA machinery: 128x128 tile, BK=32, 256 threads (4 waves 2x2),
// wave tile 64x64 = 4x4 frags of 16x16x32 f16 MFMA, 3-term hi/lo split.
// LDS plane layout [128 rows][32 k] half (row = 64 B): a wave's frag
// ds_read_b128 covers a contiguous 1 KiB region -> conflict-free.
// --------------------------------------------------------------------------

// async global->LDS staging of a pre-split half plane, 16 B per lane.
__device__ __forceinline__ void stage_gld(const half_t* __restrict__ src, size_t rowbase,
                                          int ld, int k0, half_t* __restrict__ dst, int tid) {
#pragma unroll
  for (int r = 0; r < 2; ++r) {
    const int f = tid + r * 256;          // 128 rows x 4 chunks of 8 halfs
    const half_t* g = src + (rowbase + (size_t)(f >> 2)) * (size_t)ld + k0 + (f & 3) * 8;
    const __attribute__((address_space(1))) unsigned int* gp =
        (const __attribute__((address_space(1))) unsigned int*)(uintptr_t)g;
    __attribute__((address_space(3))) unsigned int* lp =
        (__attribute__((address_space(3))) unsigned int*)(uintptr_t)(dst + f * 8);
    __builtin_amdgcn_global_load_lds(gp, lp, 16, 0, 0);
  }
}

__device__ __forceinline__ void frag_compute(const half_t* __restrict__ As_h,
                                             const half_t* __restrict__ As_l,
                                             const half_t* __restrict__ Bs_h,
                                             const half_t* __restrict__ Bs_l,
                                             f32x4 (&acc)[4][4], int lane, int wm, int wn) {
  const int lr = lane & 15, lg = lane >> 4;
  half8 ah[4], al[4], bh[4], bl[4];
#pragma unroll
  for (int i = 0; i < 4; ++i) {
    const int ar = (wm * 64 + i * 16 + lr) * 32 + lg * 8;
    ah[i] = *(const half8*)&As_h[ar];
    al[i] = *(const half8*)&As_l[ar];
    const int br = (wn * 64 + i * 16 + lr) * 32 + lg * 8;
    bh[i] = *(const half8*)&Bs_h[br];
    bl[i] = *(const half8*)&Bs_l[br];
  }
#pragma unroll
  for (int i = 0; i < 4; ++i)
#pragma unroll
    for (int j = 0; j < 4; ++j) {
      acc[i][j] = MFMA16(ah[i], bh[j], acc[i][j]);
      acc[i][j] = MFMA16(ah[i], bl[j], acc[i][j]);
      acc[i][j] = MFMA16(al[i], bh[j], acc[i][j]);
    }
}

// --------------------------------------------------------------------------
// 0) rsc[c] = 1 / softplus(scale[c])   (one tiny block)
// --------------------------------------------------------------------------
__global__ void scale_prep(const float* __restrict__ scale, float* __restrict__ scs) {
  const int c = threadIdx.x;
  scs[c] = 1.f / softplusf(scale[c]);
}

// --------------------------------------------------------------------------
// 1) Projections, register-prefetch + double-buffered LDS pipeline.
//    which==0 (q): SWAPPED operands A=Wq (rows d), B=query (rows n) so the
//    D-frag's 4-consecutive-rows land along d -> coalesced half4 stores to
//    qh/ql[n][c]. which==1/2 (k/v): A=key/value (rows m), B=W (rows c),
//    output written TRANSPOSED [b][c][m] via chunked LDS restage ->
//    fully coalesced half8 stores (fixes the 1.5x write amplification).
// --------------------------------------------------------------------------
__global__ __launch_bounds__(256) void proj_mfma(
    const float* __restrict__ query, const float* __restrict__ key,
    const float* __restrict__ value,
    const float* __restrict__ Wq, const float* __restrict__ Wk, const float* __restrict__ Wv,
    const float* __restrict__ rsc,
    half_t* __restrict__ qh, half_t* __restrict__ ql,
    half_t* __restrict__ khT, half_t* __restrict__ klT,
    half_t* __restrict__ vhT, half_t* __restrict__ vlT) {
  const int which = blockIdx.z;
  const int tid = threadIdx.x;
  const int lane = tid & 63, wave = tid >> 6, wm = wave >> 1, wn = wave & 1;
  const int lr = lane & 15, lg = lane >> 4;

  const float* srcA;
  const float* srcB;
  int rA0, rB0;
  if (which == 0) {
    srcA = Wq;    rA0 = blockIdx.y * 128;  srcB = query; rB0 = blockIdx.x * 128;
  } else if (which == 1) {
    srcA = key;   rA0 = blockIdx.x * 128;  srcB = Wk;    rB0 = blockIdx.y * 128;
  } else {
    srcA = value; rA0 = blockIdx.x * 128;  srcB = Wv;    rB0 = blockIdx.y * 128;
  }

  // 64 KB: 2 buffers x {Ah,Al,Bh,Bl} planes of 4096 halfs.
  __shared__ __align__(16) half_t sm[32768];
  f32x4 acc[4][4] = {};
  float4 RA[2][4], RB[2][4];

  auto load_tile = [&](float4 (&ra)[4], float4 (&rb)[4], int ks) {
    const int k0 = ks * 32;
#pragma unroll
    for (int r = 0; r < 4; ++r) {
      const int f = tid + r * 256;
      const int row = f >> 3, c4 = f & 7;
      ra[r] = *(const float4*)&srcA[(size_t)(rA0 + row) * 256 + k0 + c4 * 4];
      rb[r] = *(const float4*)&srcB[(size_t)(rB0 + row) * 256 + k0 + c4 * 4];
    }
  };
  auto split_write = [&](const float4 (&ra)[4], const float4 (&rb)[4], half_t* base) {
#pragma unroll
    for (int r = 0; r < 4; ++r) {
      const int f = tid + r * 256;
      const int row = f >> 3, c4 = f & 7;
      half4 h, l;
      split4(ra[r], h, l);
      *(half4*)&base[row * 32 + c4 * 4] = h;
      *(half4*)&base[4096 + row * 32 + c4 * 4] = l;
      split4(rb[r], h, l);
      *(half4*)&base[8192 + row * 32 + c4 * 4] = h;
      *(half4*)&base[12288 + row * 32 + c4 * 4] = l;
    }
  };

  // Pipeline: prologue fills buf0 + regs for tile 1; then one barrier/step.
  load_tile(RA[0], RB[0], 0);
  split_write(RA[0], RB[0], sm);
  load_tile(RA[1], RB[1], 1);
  __syncthreads();
#pragma unroll
  for (int t = 0; t < 8; ++t) {
    if (t + 2 < 8) load_tile(RA[t & 1], RB[t & 1], t + 2);
    half_t* base = sm + (t & 1) * 16384;
    frag_compute(base, base + 4096, base + 8192, base + 12288, acc, lane, wm, wn);
    if (t + 1 < 8) split_write(RA[(t + 1) & 1], RB[(t + 1) & 1], sm + ((t + 1) & 1) * 16384);
    __syncthreads();
  }

  if (which == 0) {
    // D: row = d_local (A=Wq side), col = n_local. Store along d (contiguous).
    const int dbase = rA0 + wm * 64;
    float rs[4][4];
#pragma unroll
    for (int i = 0; i < 4; ++i)
#pragma unroll
      for (int r = 0; r < 4; ++r) rs[i][r] = rsc[dbase + i * 16 + lg * 4 + r];
#pragma unroll
    for (int j = 0; j < 4; ++j) {
      const size_t nflat = (size_t)rB0 + wn * 64 + j * 16 + lr;
#pragma unroll
      for (int i = 0; i < 4; ++i) {
        half4 hv, lv;
#pragma unroll
        for (int r = 0; r < 4; ++r) {
          float v = acc[i][j][r];
          v = (fmaxf(v, 0.f) + EPSF) * rs[i][r];
          v = v * v * v;  // q**3/||q||*||q|| == q**3
          const half_t h = (half_t)v;
          hv[r] = h;
          lv[r] = (half_t)(v - (float)h);
        }
        const size_t o = nflat * 256 + dbase + i * 16 + lg * 4;
        *(half4*)&qh[o] = hv;
        *(half4*)&ql[o] = lv;
      }
    }
  } else {
    // D: row = m_local, col = c_local. Restage [32 c][128 m] chunks in LDS,
    // then coalesced half8 stores to kT/vT[b][c][m].
    const int b = rA0 >> 12, m0 = rA0 & 4095;
    half_t* Thg = (which == 1) ? khT : vhT;
    half_t* Tlg = (which == 1) ? klT : vlT;
    const bool act = (which == 1);
    half_t* Tt = sm;            // [32][136]
    half_t* Tl2 = sm + 4352;    // [32][136]
#pragma unroll
    for (int g = 0; g < 4; ++g) {
      if (wn == (g >> 1)) {
#pragma unroll
        for (int jj = 0; jj < 2; ++jj) {
          const int j = (g & 1) * 2 + jj;
          const int c = rB0 + wn * 64 + j * 16 + lr;
          const float rv = act ? rsc[c] : 1.f;
          const int crel = jj * 16 + lr;
#pragma unroll
          for (int i = 0; i < 4; ++i) {
            const int ml = wm * 64 + i * 16 + lg * 4;
            half4 hv, lv;
#pragma unroll
            for (int r = 0; r < 4; ++r) {
              float v = acc[i][j][r];
              if (act) { v = (fmaxf(v, 0.f) + EPSF) * rv; v = v * v * v; }
              const half_t h = (half_t)v;
              hv[r] = h;
              lv[r] = (half_t)(v - (float)h);
            }
            *(half4*)&Tt[crel * 136 + ml] = hv;
            *(half4*)&Tl2[crel * 136 + ml] = lv;
          }
        }
      }
      __syncthreads();
      {
        const int cr = tid >> 3, mm = (tid & 7) * 16;
        const size_t ga = ((size_t)(b * 256 + rB0 + g * 32 + cr)) * 4096 + m0 + mm;
        *(half8*)&Thg[ga]     = *(const half8*)&Tt[cr * 136 + mm];
        *(half8*)&Thg[ga + 8] = *(const half8*)&Tt[cr * 136 + mm + 8];
        *(half8*)&Tlg[ga]     = *(const half8*)&Tl2[cr * 136 + mm];
        *(half8*)&Tlg[ga + 8] = *(const half8*)&Tl2[cr * 136 + mm + 8];
      }
      __syncthreads();
    }
  }
}

// --------------------------------------------------------------------------
// 2) ksum[b][c] = sum_m k3[b][m][c], from transposed planes (m contiguous).
// --------------------------------------------------------------------------
__global__ __launch_bounds__(256) void ksum_k(const half_t* __restrict__ khT,
                                              const half_t* __restrict__ klT,
                                              float* __restrict__ ksm) {
  const int bc = blockIdx.x;  // b*256 + c
  const size_t base = (size_t)bc * 4096 + threadIdx.x * 16;
  float s = 0.f;
#pragma unroll
  for (int p = 0; p < 2; ++p) {
    const half8 h = *(const half8*)&khT[base + p * 8];
    const half8 l = *(const half8*)&klT[base + p * 8];
#pragma unroll
    for (int u = 0; u < 8; ++u) s += (float)h[u] + (float)l[u];
  }
  __shared__ float rbuf[256];
  rbuf[threadIdx.x] = s;
  __syncthreads();
  for (int off = 128; off > 0; off >>= 1) {
    if (threadIdx.x < off) rbuf[threadIdx.x] += rbuf[threadIdx.x + off];
    __syncthreads();
  }
  if (threadIdx.x == 0) ksm[bc] = rbuf[0];
}

// --------------------------------------------------------------------------
// 3) kv partials: kvT[d][c] = sum_m v[m][d]*k3[m][c]. 2-phase double-buffered
//    async staging (stage next -> compute cur -> barrier). m-split 8.
// --------------------------------------------------------------------------
__global__ __launch_bounds__(256) void kv_mfma(
    const half_t* __restrict__ vhT, const half_t* __restrict__ vlT,
    const half_t* __restrict__ khT, const half_t* __restrict__ klT,
    float* __restrict__ kvp) {
  const int b = blockIdx.z >> 3, s = blockIdx.z & 7;
  const int d0 = blockIdx.x * 128, c0 = blockIdx.y * 128;
  const int tid = threadIdx.x;
  __shared__ __align__(16) half_t sm[32768];
  f32x4 acc[4][4] = {};
  const int lane = tid & 63, wave = tid >> 6, wm = wave >> 1, wn = wave & 1;
  const int lr = lane & 15, lg = lane >> 4;
  const size_t arow = (size_t)b * 256 + d0, brow = (size_t)b * 256 + c0;

  auto stage = [&](int bi, int ks) {
    half_t* base = sm + bi * 16384;
    const int k0 = s * 512 + ks * 32;
    stage_gld(vhT, arow, 4096, k0, base, tid);
    stage_gld(vlT, arow, 4096, k0, base + 4096, tid);
    stage_gld(khT, brow, 4096, k0, base + 8192, tid);
    stage_gld(klT, brow, 4096, k0, base + 12288, tid);
  };

  stage(0, 0);
  __syncthreads();
  for (int t = 0; t < 16; ++t) {
    if (t + 1 < 16) stage((t + 1) & 1, t + 1);
    half_t* base = sm + (t & 1) * 16384;
    frag_compute(base, base + 4096, base + 8192, base + 12288, acc, lane, wm, wn);
    __syncthreads();
  }

  float* outp = kvp + ((size_t)(b * 8 + s)) * 65536;
#pragma unroll
  for (int j = 0; j < 4; ++j) {
    const int c = c0 + wn * 64 + j * 16 + lr;
#pragma unroll
    for (int i = 0; i < 4; ++i) {
      const int d = d0 + wm * 64 + i * 16 + lg * 4;
#pragma unroll
      for (int r = 0; r < 4; ++r) outp[(size_t)(d + r) * 256 + c] = acc[i][j][r];
    }
  }
}

__global__ __launch_bounds__(256) void kv_red(const float* __restrict__ kvp,
                                              half_t* __restrict__ kvTh,
                                              half_t* __restrict__ kvTl) {
  const size_t idx = (size_t)blockIdx.x * 256 + threadIdx.x;  // 524288
  const int b = (int)(idx >> 16);
  const int dc = (int)(idx & 65535);
  float s = 0.f;
#pragma unroll
  for (int t = 0; t < 8; ++t) s += kvp[((size_t)(b * 8 + t)) * 65536 + dc];
  const half_t h = (half_t)s;
  kvTh[idx] = h;
  kvTl[idx] = (half_t)(s - (float)h);
}

// --------------------------------------------------------------------------
// 4) z[b][n] = 1/(q3[b,n,:].ksum[b,:] + eps). One wave per row.
// --------------------------------------------------------------------------
__global__ __launch_bounds__(256) void z_k(const half_t* __restrict__ qh,
                                           const half_t* __restrict__ ql,
                                           const float* __restrict__ ksm,
                                           float* __restrict__ zb) {
  const int wid = threadIdx.x >> 6, lane = threadIdx.x & 63;
  const int row = blockIdx.x * 4 + wid;  // 0..32767
  const int b = row >> 12;
  const half4 h = *(const half4*)&qh[(size_t)row * 256 + lane * 4];
  const half4 l = *(const half4*)&ql[(size_t)row * 256 + lane * 4];
  const float4 kc = *(const float4*)&ksm[b * 256 + lane * 4];
  float d = ((float)h[0] + (float)l[0]) * kc.x + ((float)h[1] + (float)l[1]) * kc.y +
            ((float)h[2] + (float)l[2]) * kc.z + ((float)h[3] + (float)l[3]) * kc.w;
#pragma unroll
  for (int off = 32; off > 0; off >>= 1) d += __shfl_xor(d, off, 64);
  if (lane == 0) zb[row] = 1.f / (d + EPSF);
}

// --------------------------------------------------------------------------
// 5) x1[n][d] = (q3[n,:].kvT[d,:]) * z[n], stored transposed fp32 xt[b][d][n].
//    2-phase double-buffered async staging.
// --------------------------------------------------------------------------
__global__ __launch_bounds__(256) void x1_mfma(
    const half_t* __restrict__ qh, const half_t* __restrict__ ql,
    const half_t* __restrict__ kvTh, const half_t* __restrict__ kvTl,
    const float* __restrict__ zb, float* __restrict__ xt) {
  const int b = blockIdx.z, n0 = blockIdx.x * 128, d0t = blockIdx.y * 128;
  const int tid = threadIdx.x;
  __shared__ __align__(16) half_t sm[32768];
  f32x4 acc[4][4] = {};
  const int lane = tid & 63, wave = tid >> 6, wm = wave >> 1, wn = wave & 1;
  const int lr = lane & 15, lg = lane >> 4;
  const size_t arow = (size_t)b * 4096 + n0, brow = (size_t)b * 256 + d0t;

  auto stage = [&](int bi, int ks) {
    half_t* base = sm + bi * 16384;
    const int k0 = ks * 32;
    stage_gld(qh, arow, 256, k0, base, tid);
    stage_gld(ql, arow, 256, k0, base + 4096, tid);
    stage_gld(kvTh, brow, 256, k0, base + 8192, tid);
    stage_gld(kvTl, brow, 256, k0, base + 12288, tid);
  };

  stage(0, 0);
  __syncthreads();
  for (int t = 0; t < 8; ++t) {
    if (t + 1 < 8) stage((t + 1) & 1, t + 1);
    half_t* base = sm + (t & 1) * 16384;
    frag_compute(base, base + 4096, base + 8192, base + 12288, acc, lane, wm, wn);
    __syncthreads();
  }

#pragma unroll
  for (int i = 0; i < 4; ++i) {
    const int nb = n0 + wm * 64 + i * 16 + lg * 4;
    float zr[4];
#pragma unroll
    for (int r = 0; r < 4; ++r) zr[r] = zb[b * 4096 + nb + r];
#pragma unroll
    for (int j = 0; j < 4; ++j) {
      const int d = d0t + wn * 64 + j * 16 + lr;
      *(float4*)&xt[((size_t)b * 256 + d) * 4096 + nb] =
          make_float4(acc[i][j][0] * zr[0], acc[i][j][1] * zr[1],
                      acc[i][j][2] * zr[2], acc[i][j][3] * zr[3]);
    }
  }
}

// --------------------------------------------------------------------------
// 6) Depthwise 5x5 conv + bias on (B,C,64,64) planes (verified).
// --------------------------------------------------------------------------
__global__ __launch_bounds__(256) void dwconv_kernel(const float* __restrict__ xt,
                                                     const float* __restrict__ w,
                                                     const float* __restrict__ bias,
                                                     float* __restrict__ xc) {
  const int bc = blockIdx.x;  // b*256 + c
  const int c = bc & 255;
  const float* plane = xt + (size_t)bc * 4096;
  float* oplane = xc + (size_t)bc * 4096;

  __shared__ float Ls[68][72];
  const int tid = threadIdx.x;
  for (int i = tid; i < 68 * 72; i += 256) ((float*)Ls)[i] = 0.f;
  __syncthreads();
#pragma unroll
  for (int p = 0; p < 4; ++p) {
    const int f = tid + p * 256;
    const int y = f >> 4, x4 = f & 15;
    *(float4*)&Ls[2 + y][4 + x4 * 4] = *(const float4*)&plane[y * 64 + x4 * 4];
  }
  __syncthreads();

  float wreg[25];
#pragma unroll
  for (int t = 0; t < 25; ++t) wreg[t] = w[c * 25 + t];
  const float bv = bias[c];

  const int x = tid & 63, ys0 = (tid >> 6) * 16;
  float win[5][5];
#pragma unroll
  for (int r = 0; r < 5; ++r)
#pragma unroll
    for (int cx = 0; cx < 5; ++cx) win[r][cx] = Ls[ys0 + r][x + 2 + cx];

  for (int yy = 0; yy < 16; ++yy) {
    float s = bv;
#pragma unroll
    for (int ky = 0; ky < 5; ++ky)
#pragma unroll
      for (int kx = 0; kx < 5; ++kx) s = fmaf(win[ky][kx], wreg[ky * 5 + kx], s);
    oplane[(ys0 + yy) * 64 + x] = s;
    if (yy < 15) {
#pragma unroll
      for (int r = 0; r < 4; ++r)
#pragma unroll
        for (int cx = 0; cx < 5; ++cx) win[r][cx] = win[r + 1][cx];
#pragma unroll
      for (int cx = 0; cx < 5; ++cx) win[4][cx] = Ls[ys0 + yy + 5][x + 2 + cx];
    }
  }
}

// --------------------------------------------------------------------------
// 7) final: out[n][dd] = sum_c (xc[c][n] + q3[n][c]) * Wp[dd][c] + bp[dd].
//    Register-prefetch of all 3 sources; loads for t+1 issued at the start
//    of step t's compute phase so they overlap the MFMAs.
// --------------------------------------------------------------------------
__global__ __launch_bounds__(256) void final_mfma(
    const half_t* __restrict__ qh, const half_t* __restrict__ ql,
    const float* __restrict__ xc, const float* __restrict__ Wp,
    const float* __restrict__ bp, float* __restrict__ outp) {
  const int b = blockIdx.z, n0 = blockIdx.x * 128, dd0 = blockIdx.y * 128;
  const int tid = threadIdx.x;
  __shared__ __align__(16) half_t As_h[4096], As_l[4096], Bs_h[4096], Bs_l[4096];
  __shared__ __align__(16) float Xs[32 * 130];
  f32x4 acc[4][4] = {};
  const int lane = tid & 63, wave = tid >> 6, wm = wave >> 1, wn = wave & 1;
  const int lr = lane & 15, lg = lane >> 4;

  float4 rxs[4], rwp[4];
  half8 rqh[2][2], rql[2][2];

  auto load_xw = [&](int ks) {
    const int k0 = ks * 32;
#pragma unroll
    for (int r = 0; r < 4; ++r) {
      const int f = tid + r * 256;
      rxs[r] = *(const float4*)&xc[((size_t)b * 256 + k0 + (f >> 5)) * 4096 + n0 + (f & 31) * 4];
      rwp[r] = *(const float4*)&Wp[(size_t)(dd0 + (f >> 3)) * 256 + k0 + (f & 7) * 4];
    }
  };

  load_xw(0);
#pragma unroll
  for (int r = 0; r < 2; ++r) {
    const int f = tid + r * 256;
    const size_t qoff = ((size_t)b * 4096 + n0 + (f >> 2)) * 256 + (f & 3) * 8;
    rqh[0][r] = *(const half8*)&qh[qoff];
    rql[0][r] = *(const half8*)&ql[qoff];
  }

#pragma unroll
  for (int t = 0; t < 8; ++t) {
    // write Xs + Bs from regs (tile t)
#pragma unroll
    for (int r = 0; r < 4; ++r) {
      const int f = tid + r * 256;
      const int cc = f >> 5, n4 = f & 31;
      *(float2*)&Xs[cc * 130 + n4 * 4] = make_float2(rxs[r].x, rxs[r].y);
      *(float2*)&Xs[cc * 130 + n4 * 4 + 2] = make_float2(rxs[r].z, rxs[r].w);
      half4 h, l;
      split4(rwp[r], h, l);
      *(half4*)&Bs_h[(f >> 3) * 32 + (f & 7) * 4] = h;
      *(half4*)&Bs_l[(f >> 3) * 32 + (f & 7) * 4] = l;
    }
    __syncthreads();
    // build A = q3 + xc^T, split to hi/lo (uses rq[t&1] regs + Xs)
#pragma unroll
    for (int r = 0; r < 2; ++r) {
      const int f = tid + r * 256, row = f >> 2, ch = f & 3;
      const half8 h8 = rqh[t & 1][r];
      const half8 l8 = rql[t & 1][r];
      half8 oh, ol;
#pragma unroll
      for (int u = 0; u < 8; ++u) {
        const float v = (float)h8[u] + (float)l8[u] + Xs[(ch * 8 + u) * 130 + row];
        const half_t h = (half_t)v;
        oh[u] = h;
        ol[u] = (half_t)(v - (float)h);
      }
      *(half8*)&As_h[row * 32 + ch * 8] = oh;
      *(half8*)&As_l[row * 32 + ch * 8] = ol;
    }
    __syncthreads();
    // issue tile t+1 loads, then compute (loads overlap the MFMA phase)
    if (t + 1 < 8) {
      load_xw(t + 1);
      const int k0n = (t + 1) * 32;
#pragma unroll
      for (int r = 0; r < 2; ++r) {
        const int f = tid + r * 256;
        const size_t qoff = ((size_t)b * 4096 + n0 + (f >> 2)) * 256 + k0n + (f & 3) * 8;
        rqh[(t + 1) & 1][r] = *(const half8*)&qh[qoff];
        rql[(t + 1) & 1][r] = *(const half8*)&ql[qoff];
      }
    }
    frag_compute(As_h, As_l, Bs_h, Bs_l, acc, lane, wm, wn);
    __syncthreads();
  }

#pragma unroll
  for (int j = 0; j < 4; ++j) {
    const int dd = dd0 + wn * 64 + j * 16 + lr;
    const float bb = bp[dd];
#pragma unroll
    for (int i = 0; i < 4; ++i) {
      const size_t rowg = (size_t)b * 4096 + n0 + wm * 64 + i * 16 + lg * 4;
#pragma unroll
      for (int r = 0; r < 4; ++r) outp[(rowg + r) * 256 + dd] = acc[i][j][r] + bb;
    }
  }
}

// --------------------------------------------------------------------------
extern "C" void kernel_launch(void* const* d_in, const int* in_sizes, int n_in,
                              void* d_out, int out_size, void* d_ws, size_t ws_size,
                              hipStream_t stream) {
  const float* query = (const float*)d_in[0];
  const float* key   = (const float*)d_in[1];
  const float* value = (const float*)d_in[2];
  const float* Wq    = (const float*)d_in[3];
  const float* Wk    = (const float*)d_in[4];
  const float* Wv    = (const float*)d_in[5];
  const float* Wproj = (const float*)d_in[6];
  const float* bproj = (const float*)d_in[7];
  const float* dwc_w = (const float*)d_in[8];
  const float* dwc_b = (const float*)d_in[9];
  const float* scale = (const float*)d_in[10];

  // Workspace layout. U = 8*4096*256 elems. Peak ~119.7 MB (same as R3-ok).
  const size_t U = (size_t)8 * 4096 * 256;
  half_t* qh  = (half_t*)d_ws;            // U halfs, [b][n][c]
  half_t* ql  = qh + U;
  half_t* khT = ql + U;                   // [b][c][m] transposed
  half_t* klT = khT + U;
  half_t* vhT = klT + U;                  // [b][d][m] transposed
  half_t* vlT = vhT + U;
  float*  kvp = (float*)(vlT + U);        // 8*8*65536 fp32 partials
  half_t* kvTh = (half_t*)(kvp + (size_t)8 * 8 * 65536);  // [b][d][c]
  half_t* kvTl = kvTh + (size_t)8 * 65536;
  float*  ksm = (float*)(kvTl + (size_t)8 * 65536);       // [b][256]
  float*  zbuf = ksm + 8 * 256;                            // [32768]
  float*  scs  = zbuf + 32768;                             // [256] 1/softplus
  // aliases (reuse dead regions):
  float* xt = (float*)khT;  // x^T fp32 [b][d][n]  (khT/klT dead after kv)
  float* xc = (float*)vhT;  // conv out [b][c][n]  (vhT/vlT dead after kv)
  float* outp = (float*)d_out;

  const dim3 blk(256);
  scale_prep<<<dim3(1), blk, 0, stream>>>(scale, scs);
  proj_mfma<<<dim3(256, 2, 3), blk, 0, stream>>>(query, key, value, Wq, Wk, Wv, scs,
                                                 qh, ql, khT, klT, vhT, vlT);
  ksum_k<<<dim3(2048), blk, 0, stream>>>(khT, klT, ksm);
  kv_mfma<<<dim3(2, 2, 64), blk, 0, stream>>>(vhT, vlT, khT, klT, kvp);
  kv_red<<<dim3(2048), blk, 0, stream>>>(kvp, kvTh, kvTl);
  z_k<<<dim3(8192), blk, 0, stream>>>(qh, ql, ksm, zbuf);
  x1_mfma<<<dim3(32, 2, 8), blk, 0, stream>>>(qh, ql, kvTh, kvTl, zbuf, xt);
  dwconv_kernel<<<dim3(2048), blk, 0, stream>>>(xt, dwc_w, dwc_b, xc);
  final_mfma<<<dim3(32, 2, 8), blk, 0, stream>>>(xc == nullptr ? qh : qh, ql, xc, Wproj, bproj, outp);
}

// Round 6
// 300.375 us; speedup vs baseline: 1.7489x; 1.0305x over previous
//
#include <hip/hip_runtime.h>
#include <math.h>
#include <stdint.h>

// B=8, N=M=4096, C=256, H=W=64, KS=5 (fixed by reference).
#define EPSF 1e-6f

typedef _Float16 half_t;
typedef _Float16 half8 __attribute__((ext_vector_type(8)));
typedef _Float16 half4 __attribute__((ext_vector_type(4)));
typedef float f32x4 __attribute__((ext_vector_type(4)));

#define MFMA16(A, B, C) __builtin_amdgcn_mfma_f32_16x16x32_f16(A, B, C, 0, 0, 0)

// Raw barrier + counted waits (T3/T4): never drain vmcnt in a main loop.
#define SBAR() __builtin_amdgcn_s_barrier()
#define WAIT_LGKM0()                                        \
  do {                                                      \
    asm volatile("s_waitcnt lgkmcnt(0)" ::: "memory");      \
    __builtin_amdgcn_sched_barrier(0);                      \
  } while (0)
#define WAIT_VM8_LGKM0()                                            \
  do {                                                              \
    asm volatile("s_waitcnt vmcnt(8) lgkmcnt(0)" ::: "memory");     \
    __builtin_amdgcn_sched_barrier(0);                              \
  } while (0)
#define WAIT_VM0_LGKM0()                                            \
  do {                                                              \
    asm volatile("s_waitcnt vmcnt(0) lgkmcnt(0)" ::: "memory");     \
    __builtin_amdgcn_sched_barrier(0);                              \
  } while (0)

__device__ __forceinline__ float softplusf(float x) {
  return (x > 20.f) ? x : log1pf(expf(x));
}

__device__ __forceinline__ void split4(const float4 v, half4& h, half4& l) {
  h.x = (half_t)v.x; l.x = (half_t)(v.x - (float)h.x);
  h.y = (half_t)v.y; l.y = (half_t)(v.y - (float)h.y);
  h.z = (half_t)v.z; l.z = (half_t)(v.z - (float)h.z);
  h.w = (half_t)v.w; l.w = (half_t)(v.w - (float)h.w);
}

// --------------------------------------------------------------------------
// Shared MFMA machinery: 128x128 tile, BK=32, 256 threads (4 waves 2x2),
// wave tile 64x64 = 4x4 frags of 16x16x32 f16 MFMA, 3-term hi/lo split.
// LDS plane layout [128 rows][32 k] half (row = 64 B).
// --------------------------------------------------------------------------

__device__ __forceinline__ void stage_gld(const half_t* __restrict__ src, size_t rowbase,
                                          int ld, int k0, half_t* __restrict__ dst, int tid) {
#pragma unroll
  for (int r = 0; r < 2; ++r) {
    const int f = tid + r * 256;          // 128 rows x 4 chunks of 8 halfs
    const half_t* g = src + (rowbase + (size_t)(f >> 2)) * (size_t)ld + k0 + (f & 3) * 8;
    const __attribute__((address_space(1))) unsigned int* gp =
        (const __attribute__((address_space(1))) unsigned int*)(uintptr_t)g;
    __attribute__((address_space(3))) unsigned int* lp =
        (__attribute__((address_space(3))) unsigned int*)(uintptr_t)(dst + f * 8);
    __builtin_amdgcn_global_load_lds(gp, lp, 16, 0, 0);
  }
}

__device__ __forceinline__ void frag_compute(const half_t* __restrict__ As_h,
                                             const half_t* __restrict__ As_l,
                                             const half_t* __restrict__ Bs_h,
                                             const half_t* __restrict__ Bs_l,
                                             f32x4 (&acc)[4][4], int lane, int wm, int wn) {
  const int lr = lane & 15, lg = lane >> 4;
  half8 ah[4], al[4], bh[4], bl[4];
#pragma unroll
  for (int i = 0; i < 4; ++i) {
    const int ar = (wm * 64 + i * 16 + lr) * 32 + lg * 8;
    ah[i] = *(const half8*)&As_h[ar];
    al[i] = *(const half8*)&As_l[ar];
    const int br = (wn * 64 + i * 16 + lr) * 32 + lg * 8;
    bh[i] = *(const half8*)&Bs_h[br];
    bl[i] = *(const half8*)&Bs_l[br];
  }
#pragma unroll
  for (int i = 0; i < 4; ++i)
#pragma unroll
    for (int j = 0; j < 4; ++j) {
      acc[i][j] = MFMA16(ah[i], bh[j], acc[i][j]);
      acc[i][j] = MFMA16(ah[i], bl[j], acc[i][j]);
      acc[i][j] = MFMA16(al[i], bh[j], acc[i][j]);
    }
}

// --------------------------------------------------------------------------
// 0) init: scs[c] = 1/softplus(scale[c]); zero ksm (proj atomicAdds into it).
// --------------------------------------------------------------------------
__global__ void init_k(const float* __restrict__ scale, float* __restrict__ scs,
                       float* __restrict__ ksm) {
  const int i = blockIdx.x * 256 + threadIdx.x;
  if (i < 2048) ksm[i] = 0.f;
  if (i < 256) scs[i] = 1.f / softplusf(scale[i]);
}

// --------------------------------------------------------------------------
// 1) Projections: reg-prefetch + LDS dbuf, ONE raw barrier per K-step
//    (lgkmcnt-only: prefetch loads stay in flight across the barrier).
//    which==0 (q): A=Wq, B=query -> coalesced half4 stores along d.
//    which==1/2 (k/v): transposed [b][c][m] out via chunked LDS restage.
//    which==1 additionally atomicAdds ksum partials into ksm.
// --------------------------------------------------------------------------
__global__ __launch_bounds__(256) void proj_mfma(
    const float* __restrict__ query, const float* __restrict__ key,
    const float* __restrict__ value,
    const float* __restrict__ Wq, const float* __restrict__ Wk, const float* __restrict__ Wv,
    const float* __restrict__ rsc,
    half_t* __restrict__ qh, half_t* __restrict__ ql,
    half_t* __restrict__ khT, half_t* __restrict__ klT,
    half_t* __restrict__ vhT, half_t* __restrict__ vlT,
    float* __restrict__ ksm) {
  const int which = blockIdx.z;
  const int tid = threadIdx.x;
  const int lane = tid & 63, wave = tid >> 6, wm = wave >> 1, wn = wave & 1;
  const int lr = lane & 15, lg = lane >> 4;

  const float* srcA;
  const float* srcB;
  int rA0, rB0;
  if (which == 0) {
    srcA = Wq;    rA0 = blockIdx.y * 128;  srcB = query; rB0 = blockIdx.x * 128;
  } else if (which == 1) {
    srcA = key;   rA0 = blockIdx.x * 128;  srcB = Wk;    rB0 = blockIdx.y * 128;
  } else {
    srcA = value; rA0 = blockIdx.x * 128;  srcB = Wv;    rB0 = blockIdx.y * 128;
  }

  __shared__ __align__(16) half_t sm[32768];  // 2 x {Ah,Al,Bh,Bl} x 4096
  f32x4 acc[4][4] = {};
  float4 RA[2][4], RB[2][4];

  auto load_tile = [&](float4 (&ra)[4], float4 (&rb)[4], int ks) {
    const int k0 = ks * 32;
#pragma unroll
    for (int r = 0; r < 4; ++r) {
      const int f = tid + r * 256;
      const int row = f >> 3, c4 = f & 7;
      ra[r] = *(const float4*)&srcA[(size_t)(rA0 + row) * 256 + k0 + c4 * 4];
      rb[r] = *(const float4*)&srcB[(size_t)(rB0 + row) * 256 + k0 + c4 * 4];
    }
  };
  auto split_write = [&](const float4 (&ra)[4], const float4 (&rb)[4], half_t* base) {
#pragma unroll
    for (int r = 0; r < 4; ++r) {
      const int f = tid + r * 256;
      const int row = f >> 3, c4 = f & 7;
      half4 h, l;
      split4(ra[r], h, l);
      *(half4*)&base[row * 32 + c4 * 4] = h;
      *(half4*)&base[4096 + row * 32 + c4 * 4] = l;
      split4(rb[r], h, l);
      *(half4*)&base[8192 + row * 32 + c4 * 4] = h;
      *(half4*)&base[12288 + row * 32 + c4 * 4] = l;
    }
  };

  load_tile(RA[0], RB[0], 0);
  split_write(RA[0], RB[0], sm);
  load_tile(RA[1], RB[1], 1);
  WAIT_LGKM0();
  SBAR();
#pragma unroll
  for (int t = 0; t < 8; ++t) {
    if (t + 2 < 8) load_tile(RA[t & 1], RB[t & 1], t + 2);
    half_t* base = sm + (t & 1) * 16384;
    frag_compute(base, base + 4096, base + 8192, base + 12288, acc, lane, wm, wn);
    if (t + 1 < 8) split_write(RA[(t + 1) & 1], RB[(t + 1) & 1], sm + ((t + 1) & 1) * 16384);
    WAIT_LGKM0();
    SBAR();
  }

  if (which == 0) {
    // D: row = d_local (A=Wq side), col = n_local. Store along d (contiguous).
    const int dbase = rA0 + wm * 64;
    float rs[4][4];
#pragma unroll
    for (int i = 0; i < 4; ++i)
#pragma unroll
      for (int r = 0; r < 4; ++r) rs[i][r] = rsc[dbase + i * 16 + lg * 4 + r];
#pragma unroll
    for (int j = 0; j < 4; ++j) {
      const size_t nflat = (size_t)rB0 + wn * 64 + j * 16 + lr;
#pragma unroll
      for (int i = 0; i < 4; ++i) {
        half4 hv, lv;
#pragma unroll
        for (int r = 0; r < 4; ++r) {
          float v = acc[i][j][r];
          v = (fmaxf(v, 0.f) + EPSF) * rs[i][r];
          v = v * v * v;  // q**3/||q||*||q|| == q**3
          const half_t h = (half_t)v;
          hv[r] = h;
          lv[r] = (half_t)(v - (float)h);
        }
        const size_t o = nflat * 256 + dbase + i * 16 + lg * 4;
        *(half4*)&qh[o] = hv;
        *(half4*)&ql[o] = lv;
      }
    }
  } else {
    // D: row = m_local, col = c_local. Restage [32 c][128 m] chunks in LDS,
    // then coalesced half8 stores. which==1: accumulate ksum partials too.
    const int b = rA0 >> 12, m0 = rA0 & 4095;
    half_t* Thg = (which == 1) ? khT : vhT;
    half_t* Tlg = (which == 1) ? klT : vlT;
    const bool act = (which == 1);
    half_t* Tt = sm;            // [32][136]
    half_t* Tl2 = sm + 4352;    // [32][136]
    float kj[4] = {0.f, 0.f, 0.f, 0.f};
#pragma unroll
    for (int g = 0; g < 4; ++g) {
      if (wn == (g >> 1)) {
#pragma unroll
        for (int jj = 0; jj < 2; ++jj) {
          const int j = (g & 1) * 2 + jj;
          const int c = rB0 + wn * 64 + j * 16 + lr;
          const float rv = act ? rsc[c] : 1.f;
          const int crel = jj * 16 + lr;
#pragma unroll
          for (int i = 0; i < 4; ++i) {
            const int ml = wm * 64 + i * 16 + lg * 4;
            half4 hv, lv;
#pragma unroll
            for (int r = 0; r < 4; ++r) {
              float v = acc[i][j][r];
              if (act) { v = (fmaxf(v, 0.f) + EPSF) * rv; v = v * v * v; kj[j] += v; }
              const half_t h = (half_t)v;
              hv[r] = h;
              lv[r] = (half_t)(v - (float)h);
            }
            *(half4*)&Tt[crel * 136 + ml] = hv;
            *(half4*)&Tl2[crel * 136 + ml] = lv;
          }
        }
      }
      __syncthreads();
      {
        const int cr = tid >> 3, mm = (tid & 7) * 16;
        const size_t ga = ((size_t)(b * 256 + rB0 + g * 32 + cr)) * 4096 + m0 + mm;
        *(half8*)&Thg[ga]     = *(const half8*)&Tt[cr * 136 + mm];
        *(half8*)&Thg[ga + 8] = *(const half8*)&Tt[cr * 136 + mm + 8];
        *(half8*)&Tlg[ga]     = *(const half8*)&Tl2[cr * 136 + mm];
        *(half8*)&Tlg[ga + 8] = *(const half8*)&Tl2[cr * 136 + mm + 8];
      }
      __syncthreads();
    }
    if (act) {
      // kj[j]: this thread's sum over its 16 m for col j. Reduce over lg
      // (lanes lr+16*lg) then one atomicAdd per (wave, j, lr).
#pragma unroll
      for (int j = 0; j < 4; ++j) {
        float s = kj[j];
        s += __shfl_xor(s, 16, 64);
        s += __shfl_xor(s, 32, 64);
        if (lg == 0) atomicAdd(&ksm[b * 256 + rB0 + wn * 64 + j * 16 + lr], s);
      }
    }
  }
}

// --------------------------------------------------------------------------
// 3) kv partials: kvT[d][c] = sum_m v[m][d]*k3[m][c]. 3-deep gld ring with
//    counted vmcnt(8): t+2's loads stay in flight across each barrier.
// --------------------------------------------------------------------------
__global__ __launch_bounds__(256) void kv_mfma(
    const half_t* __restrict__ vhT, const half_t* __restrict__ vlT,
    const half_t* __restrict__ khT, const half_t* __restrict__ klT,
    float* __restrict__ kvp) {
  const int b = blockIdx.z >> 3, s = blockIdx.z & 7;
  const int d0 = blockIdx.x * 128, c0 = blockIdx.y * 128;
  const int tid = threadIdx.x;
  __shared__ __align__(16) half_t sm[49152];  // 3 bufs x 16384 halfs
  f32x4 acc[4][4] = {};
  const int lane = tid & 63, wave = tid >> 6, wm = wave >> 1, wn = wave & 1;
  const int lr = lane & 15, lg = lane >> 4;
  const size_t arow = (size_t)b * 256 + d0, brow = (size_t)b * 256 + c0;

  auto stage = [&](int bi, int ks) {
    half_t* base = sm + bi * 16384;
    const int k0 = s * 512 + ks * 32;
    stage_gld(vhT, arow, 4096, k0, base, tid);
    stage_gld(vlT, arow, 4096, k0, base + 4096, tid);
    stage_gld(khT, brow, 4096, k0, base + 8192, tid);
    stage_gld(klT, brow, 4096, k0, base + 12288, tid);
  };

  stage(0, 0);
  stage(1, 1);
  WAIT_VM8_LGKM0();   // buf0 landed; buf1's 8 in flight
  SBAR();
#pragma unroll
  for (int t = 0; t < 16; ++t) {
    if (t + 2 < 16) stage((t + 2) % 3, t + 2);
    half_t* base = sm + (t % 3) * 16384;
    frag_compute(base, base + 4096, base + 8192, base + 12288, acc, lane, wm, wn);
    if (t + 2 < 16) { WAIT_VM8_LGKM0(); } else { WAIT_VM0_LGKM0(); }
    SBAR();
  }

  float* outp = kvp + ((size_t)(b * 8 + s)) * 65536;
#pragma unroll
  for (int j = 0; j < 4; ++j) {
    const int c = c0 + wn * 64 + j * 16 + lr;
#pragma unroll
    for (int i = 0; i < 4; ++i) {
      const int d = d0 + wm * 64 + i * 16 + lg * 4;
#pragma unroll
      for (int r = 0; r < 4; ++r) outp[(size_t)(d + r) * 256 + c] = acc[i][j][r];
    }
  }
}

__global__ __launch_bounds__(256) void kv_red(const float* __restrict__ kvp,
                                              half_t* __restrict__ kvTh,
                                              half_t* __restrict__ kvTl) {
  const size_t idx = (size_t)blockIdx.x * 256 + threadIdx.x;  // 524288
  const int b = (int)(idx >> 16);
  const int dc = (int)(idx & 65535);
  float s = 0.f;
#pragma unroll
  for (int t = 0; t < 8; ++t) s += kvp[((size_t)(b * 8 + t)) * 65536 + dc];
  const half_t h = (half_t)s;
  kvTh[idx] = h;
  kvTl[idx] = (half_t)(s - (float)h);
}

// --------------------------------------------------------------------------
// 5) x1[n][d] = (q3[n,:].kvT[d,:]) * z[n], z computed IN-KERNEL from the
//    staged q planes (z[n] = 1/(q3[n,:].ksum + eps)). 3-deep gld ring,
//    counted vmcnt. Output transposed fp32 xt[b][d][n].
// --------------------------------------------------------------------------
__global__ __launch_bounds__(256) void x1_mfma(
    const half_t* __restrict__ qh, const half_t* __restrict__ ql,
    const half_t* __restrict__ kvTh, const half_t* __restrict__ kvTl,
    const float* __restrict__ ksm, float* __restrict__ xt) {
  const int b = blockIdx.z, n0 = blockIdx.x * 128, d0t = blockIdx.y * 128;
  const int tid = threadIdx.x;
  __shared__ __align__(16) half_t sm[49152];
  __shared__ float zden[128];
  f32x4 acc[4][4] = {};
  const int lane = tid & 63, wave = tid >> 6, wm = wave >> 1, wn = wave & 1;
  const int lr = lane & 15, lg = lane >> 4;
  const size_t arow = (size_t)b * 4096 + n0, brow = (size_t)b * 256 + d0t;

  auto stage = [&](int bi, int ks) {
    half_t* base = sm + bi * 16384;
    const int k0 = ks * 32;
    stage_gld(qh, arow, 256, k0, base, tid);
    stage_gld(ql, arow, 256, k0, base + 4096, tid);
    stage_gld(kvTh, brow, 256, k0, base + 8192, tid);
    stage_gld(kvTl, brow, 256, k0, base + 12288, tid);
  };

  stage(0, 0);
  stage(1, 1);
  WAIT_VM8_LGKM0();
  SBAR();
  float zpart = 0.f;
  const int zrow = tid >> 1, zkh = tid & 1;
#pragma unroll
  for (int t = 0; t < 8; ++t) {
    if (t + 2 < 8) stage((t + 2) % 3, t + 2);
    half_t* base = sm + (t % 3) * 16384;
    frag_compute(base, base + 4096, base + 8192, base + 12288, acc, lane, wm, wn);
    {  // z partial: q3 row dot ksum for this k-chunk (reads staged planes)
      const half_t* hp = base + zrow * 32 + zkh * 16;
      const half_t* lp = base + 4096 + zrow * 32 + zkh * 16;
      const half8 h0 = *(const half8*)&hp[0];
      const half8 h1 = *(const half8*)&hp[8];
      const half8 l0 = *(const half8*)&lp[0];
      const half8 l1 = *(const half8*)&lp[8];
      const float* ksp = ksm + b * 256 + t * 32 + zkh * 16;
#pragma unroll
      for (int u = 0; u < 8; ++u) {
        zpart += ((float)h0[u] + (float)l0[u]) * ksp[u];
        zpart += ((float)h1[u] + (float)l1[u]) * ksp[8 + u];
      }
    }
    if (t + 2 < 8) { WAIT_VM8_LGKM0(); } else { WAIT_VM0_LGKM0(); }
    SBAR();
  }

  zpart += __shfl_xor(zpart, 1, 64);
  if ((tid & 1) == 0) zden[zrow] = zpart;
  __syncthreads();

#pragma unroll
  for (int i = 0; i < 4; ++i) {
    const int nl = wm * 64 + i * 16 + lg * 4;  // local row in [0,128)
    float zr[4];
#pragma unroll
    for (int r = 0; r < 4; ++r) zr[r] = 1.f / (zden[nl + r] + EPSF);
#pragma unroll
    for (int j = 0; j < 4; ++j) {
      const int d = d0t + wn * 64 + j * 16 + lr;
      *(float4*)&xt[((size_t)b * 256 + d) * 4096 + n0 + nl] =
          make_float4(acc[i][j][0] * zr[0], acc[i][j][1] * zr[1],
                      acc[i][j][2] * zr[2], acc[i][j][3] * zr[3]);
    }
  }
}

// --------------------------------------------------------------------------
// 6) Depthwise 5x5 conv + bias on (B,C,64,64) planes (verified).
// --------------------------------------------------------------------------
__global__ __launch_bounds__(256) void dwconv_kernel(const float* __restrict__ xt,
                                                     const float* __restrict__ w,
                                                     const float* __restrict__ bias,
                                                     float* __restrict__ xc) {
  const int bc = blockIdx.x;  // b*256 + c
  const int c = bc & 255;
  const float* plane = xt + (size_t)bc * 4096;
  float* oplane = xc + (size_t)bc * 4096;

  __shared__ float Ls[68][72];
  const int tid = threadIdx.x;
  for (int i = tid; i < 68 * 72; i += 256) ((float*)Ls)[i] = 0.f;
  __syncthreads();
#pragma unroll
  for (int p = 0; p < 4; ++p) {
    const int f = tid + p * 256;
    const int y = f >> 4, x4 = f & 15;
    *(float4*)&Ls[2 + y][4 + x4 * 4] = *(const float4*)&plane[y * 64 + x4 * 4];
  }
  __syncthreads();

  float wreg[25];
#pragma unroll
  for (int t = 0; t < 25; ++t) wreg[t] = w[c * 25 + t];
  const float bv = bias[c];

  const int x = tid & 63, ys0 = (tid >> 6) * 16;
  float win[5][5];
#pragma unroll
  for (int r = 0; r < 5; ++r)
#pragma unroll
    for (int cx = 0; cx < 5; ++cx) win[r][cx] = Ls[ys0 + r][x + 2 + cx];

  for (int yy = 0; yy < 16; ++yy) {
    float s = bv;
#pragma unroll
    for (int ky = 0; ky < 5; ++ky)
#pragma unroll
      for (int kx = 0; kx < 5; ++kx) s = fmaf(win[ky][kx], wreg[ky * 5 + kx], s);
    oplane[(ys0 + yy) * 64 + x] = s;
    if (yy < 15) {
#pragma unroll
      for (int r = 0; r < 4; ++r)
#pragma unroll
        for (int cx = 0; cx < 5; ++cx) win[r][cx] = win[r + 1][cx];
#pragma unroll
      for (int cx = 0; cx < 5; ++cx) win[4][cx] = Ls[ys0 + yy + 5][x + 2 + cx];
    }
  }
}

// --------------------------------------------------------------------------
// 7) final: out[n][dd] = sum_c (xc[c][n] + q3[n][c]) * Wp[dd][c] + bp[dd].
//    Raw barriers (lgkm-only) so t+1 register loads span the sync points.
// --------------------------------------------------------------------------
__global__ __launch_bounds__(256) void final_mfma(
    const half_t* __restrict__ qh, const half_t* __restrict__ ql,
    const float* __restrict__ xc, const float* __restrict__ Wp,
    const float* __restrict__ bp, float* __restrict__ outp) {
  const int b = blockIdx.z, n0 = blockIdx.x * 128, dd0 = blockIdx.y * 128;
  const int tid = threadIdx.x;
  __shared__ __align__(16) half_t As_h[4096], As_l[4096], Bs_h[4096], Bs_l[4096];
  __shared__ __align__(16) float Xs[32 * 130];
  f32x4 acc[4][4] = {};
  const int lane = tid & 63, wave = tid >> 6, wm = wave >> 1, wn = wave & 1;
  const int lr = lane & 15, lg = lane >> 4;

  float4 rxs[4], rwp[4];
  half8 rqh[2][2], rql[2][2];

  auto load_xw = [&](int ks) {
    const int k0 = ks * 32;
#pragma unroll
    for (int r = 0; r < 4; ++r) {
      const int f = tid + r * 256;
      rxs[r] = *(const float4*)&xc[((size_t)b * 256 + k0 + (f >> 5)) * 4096 + n0 + (f & 31) * 4];
      rwp[r] = *(const float4*)&Wp[(size_t)(dd0 + (f >> 3)) * 256 + k0 + (f & 7) * 4];
    }
  };

  load_xw(0);
#pragma unroll
  for (int r = 0; r < 2; ++r) {
    const int f = tid + r * 256;
    const size_t qoff = ((size_t)b * 4096 + n0 + (f >> 2)) * 256 + (f & 3) * 8;
    rqh[0][r] = *(const half8*)&qh[qoff];
    rql[0][r] = *(const half8*)&ql[qoff];
  }

#pragma unroll
  for (int t = 0; t < 8; ++t) {
#pragma unroll
    for (int r = 0; r < 4; ++r) {
      const int f = tid + r * 256;
      const int cc = f >> 5, n4 = f & 31;
      *(float2*)&Xs[cc * 130 + n4 * 4] = make_float2(rxs[r].x, rxs[r].y);
      *(float2*)&Xs[cc * 130 + n4 * 4 + 2] = make_float2(rxs[r].z, rxs[r].w);
      half4 h, l;
      split4(rwp[r], h, l);
      *(half4*)&Bs_h[(f >> 3) * 32 + (f & 7) * 4] = h;
      *(half4*)&Bs_l[(f >> 3) * 32 + (f & 7) * 4] = l;
    }
    WAIT_LGKM0();
    SBAR();
#pragma unroll
    for (int r = 0; r < 2; ++r) {
      const int f = tid + r * 256, row = f >> 2, ch = f & 3;
      const half8 h8 = rqh[t & 1][r];
      const half8 l8 = rql[t & 1][r];
      half8 oh, ol;
#pragma unroll
      for (int u = 0; u < 8; ++u) {
        const float v = (float)h8[u] + (float)l8[u] + Xs[(ch * 8 + u) * 130 + row];
        const half_t h = (half_t)v;
        oh[u] = h;
        ol[u] = (half_t)(v - (float)h);
      }
      *(half8*)&As_h[row * 32 + ch * 8] = oh;
      *(half8*)&As_l[row * 32 + ch * 8] = ol;
    }
    WAIT_LGKM0();
    SBAR();
    if (t + 1 < 8) {
      load_xw(t + 1);
      const int k0n = (t + 1) * 32;
#pragma unroll
      for (int r = 0; r < 2; ++r) {
        const int f = tid + r * 256;
        const size_t qoff = ((size_t)b * 4096 + n0 + (f >> 2)) * 256 + k0n + (f & 3) * 8;
        rqh[(t + 1) & 1][r] = *(const half8*)&qh[qoff];
        rql[(t + 1) & 1][r] = *(const half8*)&ql[qoff];
      }
    }
    frag_compute(As_h, As_l, Bs_h, Bs_l, acc, lane, wm, wn);
    WAIT_LGKM0();
    SBAR();
  }

#pragma unroll
  for (int j = 0; j < 4; ++j) {
    const int dd = dd0 + wn * 64 + j * 16 + lr;
    const float bb = bp[dd];
#pragma unroll
    for (int i = 0; i < 4; ++i) {
      const size_t rowg = (size_t)b * 4096 + n0 + wm * 64 + i * 16 + lg * 4;
#pragma unroll
      for (int r = 0; r < 4; ++r) outp[(rowg + r) * 256 + dd] = acc[i][j][r] + bb;
    }
  }
}

// --------------------------------------------------------------------------
extern "C" void kernel_launch(void* const* d_in, const int* in_sizes, int n_in,
                              void* d_out, int out_size, void* d_ws, size_t ws_size,
                              hipStream_t stream) {
  const float* query = (const float*)d_in[0];
  const float* key   = (const float*)d_in[1];
  const float* value = (const float*)d_in[2];
  const float* Wq    = (const float*)d_in[3];
  const float* Wk    = (const float*)d_in[4];
  const float* Wv    = (const float*)d_in[5];
  const float* Wproj = (const float*)d_in[6];
  const float* bproj = (const float*)d_in[7];
  const float* dwc_w = (const float*)d_in[8];
  const float* dwc_b = (const float*)d_in[9];
  const float* scale = (const float*)d_in[10];

  // Workspace layout. U = 8*4096*256 elems. Peak ~119.7 MB.
  const size_t U = (size_t)8 * 4096 * 256;
  half_t* qh  = (half_t*)d_ws;            // U halfs, [b][n][c]
  half_t* ql  = qh + U;
  half_t* khT = ql + U;                   // [b][c][m] transposed
  half_t* klT = khT + U;
  half_t* vhT = klT + U;                  // [b][d][m] transposed
  half_t* vlT = vhT + U;
  float*  kvp = (float*)(vlT + U);        // 8*8*65536 fp32 partials
  half_t* kvTh = (half_t*)(kvp + (size_t)8 * 8 * 65536);  // [b][d][c]
  half_t* kvTl = kvTh + (size_t)8 * 65536;
  float*  ksm = (float*)(kvTl + (size_t)8 * 65536);       // [b][256]
  float*  zbuf = ksm + 8 * 256;                            // (unused, kept)
  float*  scs  = zbuf + 32768;                             // [256] 1/softplus
  // aliases (reuse dead regions):
  float* xt = (float*)khT;  // x^T fp32 [b][d][n]  (khT/klT dead after kv)
  float* xc = (float*)vhT;  // conv out [b][c][n]  (vhT/vlT dead after kv)
  float* outp = (float*)d_out;

  const dim3 blk(256);
  init_k<<<dim3(8), blk, 0, stream>>>(scale, scs, ksm);
  proj_mfma<<<dim3(256, 2, 3), blk, 0, stream>>>(query, key, value, Wq, Wk, Wv, scs,
                                                 qh, ql, khT, klT, vhT, vlT, ksm);
  kv_mfma<<<dim3(2, 2, 64), blk, 0, stream>>>(vhT, vlT, khT, klT, kvp);
  kv_red<<<dim3(2048), blk, 0, stream>>>(kvp, kvTh, kvTl);
  x1_mfma<<<dim3(32, 2, 8), blk, 0, stream>>>(qh, ql, kvTh, kvTl, ksm, xt);
  dwconv_kernel<<<dim3(2048), blk, 0, stream>>>(xt, dwc_w, dwc_b, xc);
  final_mfma<<<dim3(32, 2, 8), blk, 0, stream>>>(qh, ql, xc, Wproj, bproj, outp);
}